// Round 16
// baseline (394.911 us; speedup 1.0000x reference)
//
#include <hip/hip_runtime.h>
#include <hip/hip_bf16.h>

typedef __hip_bfloat16 bf16;
typedef short s16x8 __attribute__((ext_vector_type(8)));
typedef short s16x4 __attribute__((ext_vector_type(4)));
typedef float f32x4 __attribute__((ext_vector_type(4)));

#define SCALE_DH 0.11180339887498949f   // 80^-0.5
#define QSCALE   0.16129820878f         // 80^-0.5 * log2(e)

static __device__ __forceinline__ float b2f(short u) {
  union { float f; unsigned int i; } x;
  x.i = ((unsigned int)(unsigned short)u) << 16;
  return x.f;
}

static __device__ __forceinline__ float tof(float x) { return x; }
static __device__ __forceinline__ float tof(bf16 x) { return __bfloat162float(x); }

static __device__ __forceinline__ void gload16(const bf16* g, bf16* l) {
  __builtin_amdgcn_global_load_lds((__attribute__((address_space(1))) const void*)g,
                                   (__attribute__((address_space(3))) void*)l, 16, 0, 0);
}

// ---------------- fused weight prep: 10 transposes + 1 cvt in one launch ----------------
struct PrepArgs {
  const float* src[10];
  bf16* dst[10];
  int R[10], C[10], cb[10], base[10];
  int cvtbase;
  const float* ctx;
  bf16* ctxb;
};

__global__ __launch_bounds__(256) void prep_kernel(PrepArgs a) {
  const int bid = blockIdx.x;
  if (bid >= a.cvtbase) {
    const int n = 154 * 768;
    int i = ((bid - a.cvtbase) * 256 + threadIdx.x) * 4;
    if (i + 4 <= n) {
      float4 v = *(const float4*)(a.ctx + i);
      a.ctxb[i + 0] = __float2bfloat16(v.x);
      a.ctxb[i + 1] = __float2bfloat16(v.y);
      a.ctxb[i + 2] = __float2bfloat16(v.z);
      a.ctxb[i + 3] = __float2bfloat16(v.w);
    } else {
      for (int k = i; k < n; ++k) a.ctxb[k] = __float2bfloat16(a.ctx[k]);
    }
    return;
  }
  int jid = 0;
#pragma unroll
  for (int k = 1; k < 10; ++k)
    if (bid >= a.base[k]) jid = k;
  const float* in = a.src[jid];
  bf16* out = a.dst[jid];
  const int R = a.R[jid], C = a.C[jid];
  const int lb = bid - a.base[jid];
  const int cblk = lb % a.cb[jid], rblk = lb / a.cb[jid];
  __shared__ float t[32][33];
  const int tx = threadIdx.x & 31, ty = threadIdx.x >> 5;
  const long r0 = (long)rblk * 32, c0 = (long)cblk * 32;
#pragma unroll
  for (int i = 0; i < 4; ++i)
    t[ty + 8 * i][tx] = in[(r0 + ty + 8 * i) * C + c0 + tx];
  __syncthreads();
#pragma unroll
  for (int i = 0; i < 4; ++i)
    out[(c0 + ty + 8 * i) * R + r0 + tx] = __float2bfloat16(t[tx][ty + 8 * i]);
}

// ---------------- LayerNorm D=640: T in -> bf16 out (one wave per row) ----------------
template <typename T>
__global__ __launch_bounds__(256) void ln_kernel(const T* __restrict__ x,
                                                 const float* __restrict__ w,
                                                 const float* __restrict__ b,
                                                 bf16* __restrict__ out) {
  const int wv = threadIdx.x >> 6, l = threadIdx.x & 63;
  const long row = (long)blockIdx.x * 4 + wv;
  const T* xr = x + row * 640;
  float v[10];
  float s = 0.f;
#pragma unroll
  for (int j = 0; j < 10; ++j) { v[j] = tof(xr[l + 64 * j]); s += v[j]; }
#pragma unroll
  for (int o = 32; o > 0; o >>= 1) s += __shfl_xor(s, o);
  const float mean = s * (1.f / 640.f);
  float vs = 0.f;
#pragma unroll
  for (int j = 0; j < 10; ++j) { float d = v[j] - mean; vs += d * d; }
#pragma unroll
  for (int o = 32; o > 0; o >>= 1) vs += __shfl_xor(vs, o);
  const float rstd = rsqrtf(vs * (1.f / 640.f) + 1e-5f);
  bf16* orow = out + row * 640;
#pragma unroll
  for (int j = 0; j < 10; ++j) {
    int d = l + 64 * j;
    orow[d] = __float2bfloat16((v[j] - mean) * rstd * w[d] + b[d]);
  }
}

// ---------------- GEMM 128x128: C[M,N] = A[M,K](bf16) * W, Bt = W^T [N][K] ----------------
// EPI 0: bf16 out. EPI 3 (QKV): bf16 out for col<1280; V cols written TRANSPOSED to vt (res param).
template <int EPI>
__global__ __launch_bounds__(256) void gemm_kernel(const bf16* __restrict__ A,
                                                   const bf16* __restrict__ Bt,
                                                   const float* __restrict__ bias,
                                                   const float* __restrict__ res,
                                                   void* __restrict__ Cout,
                                                   int M, int K, int ldc) {
  __shared__ bf16 Ash[128 * 64];
  __shared__ bf16 Bsh[128 * 64];
  const int tid = threadIdx.x, w = tid >> 6, l = tid & 63;
  const int m0 = blockIdx.x * 128, n0 = blockIdx.y * 128;
  const int mb = (w >> 1) * 64, nb = (w & 1) * 64;
  const int lo = l & 15, lg = l >> 4, lo7 = l & 7;
  const f32x4 fz = {0.f, 0.f, 0.f, 0.f};
  f32x4 acc[4][4];
#pragma unroll
  for (int i = 0; i < 4; ++i)
#pragma unroll
    for (int j = 0; j < 4; ++j) acc[i][j] = fz;

  const int g = tid;
  const int gr = g >> 3;
  const int gcsw = 8 * ((g & 7) ^ (gr & 7));
  const bf16* pa[4];
  const bf16* pb[4];
  bf16* la[4];
  bf16* lb[4];
#pragma unroll
  for (int s = 0; s < 4; ++s) {
    const int rl = gr + 32 * s;
    int ra = m0 + rl; if (ra >= M) ra = M - 1;
    pa[s] = A + (long)ra * K + gcsw;
    pb[s] = Bt + (long)(n0 + rl) * K + gcsw;
    la[s] = Ash + (g + 256 * s) * 8;
    lb[s] = Bsh + (g + 256 * s) * 8;
  }

  for (int k0 = 0; k0 < K; k0 += 64) {
    __syncthreads();
#pragma unroll
    for (int s = 0; s < 4; ++s) {
      gload16(pa[s], la[s]); pa[s] += 64;
      gload16(pb[s], lb[s]); pb[s] += 64;
    }
    __syncthreads();
#pragma unroll
    for (int kk = 0; kk < 2; ++kk) {
      const int sl = ((kk * 4 + lg) ^ lo7) * 8;
      s16x8 a[4], b[4];
#pragma unroll
      for (int i = 0; i < 4; ++i)
        a[i] = *(const s16x8*)(Ash + (mb + i * 16 + lo) * 64 + sl);
#pragma unroll
      for (int j = 0; j < 4; ++j)
        b[j] = *(const s16x8*)(Bsh + (nb + j * 16 + lo) * 64 + sl);
#pragma unroll
      for (int i = 0; i < 4; ++i)
#pragma unroll
        for (int j = 0; j < 4; ++j)
          acc[i][j] = __builtin_amdgcn_mfma_f32_16x16x32_bf16(a[i], b[j], acc[i][j], 0, 0, 0);
    }
  }
  const int rb = m0 + mb + lg * 4;
  const int cb = n0 + nb + lo;
#pragma unroll
  for (int i = 0; i < 4; ++i) {
#pragma unroll
    for (int j = 0; j < 4; ++j) {
      const int col = cb + j * 16;
      if (EPI == 3 && col >= 1280) {
        const int t = col - 1280;
        const int hh = t / 80, dh = t % 80;
        const int row0 = rb + i * 16;
        const int bb = row0 >> 12, n = row0 & 4095;
        s16x4 pk;
#pragma unroll
        for (int r = 0; r < 4; ++r)
          pk[r] = (short)__bfloat16_as_ushort(__float2bfloat16(acc[i][j][r]));
        bf16* vt = (bf16*)res;
        *(s16x4*)(vt + (long)(bb * 8 + hh) * 327680 + (long)dh * 4096 + n) = pk;
        continue;
      }
#pragma unroll
      for (int r = 0; r < 4; ++r) {
        const int row = rb + i * 16 + r;
        if (row < M)
          ((bf16*)Cout)[(long)row * ldc + col] = __float2bfloat16(acc[i][j][r]);
      }
    }
  }
}

// ---------------- GEMM 64x128 (N=640 GEMMs; M % 64 == 0) ----------------
// EPI 0: bf16 out, no bias. EPI 4: bf16 out = acc+bias+f32 res. EPI 5: bf16 out = acc+bias+bf16 res.
// EPI 6: f32 out = acc+bias+bf16 res.
template <int EPI>
__global__ __launch_bounds__(256) void gemm64_kernel(const bf16* __restrict__ A,
                                                     const bf16* __restrict__ Bt,
                                                     const float* __restrict__ bias,
                                                     const void* __restrict__ res,
                                                     void* __restrict__ Cout,
                                                     int K, int ldc) {
  __shared__ bf16 Ash[64 * 64];
  __shared__ bf16 Bsh[128 * 64];
  const int tid = threadIdx.x, w = tid >> 6, l = tid & 63;
  const int m0 = blockIdx.x * 64, n0 = blockIdx.y * 128;
  const int mb = (w & 1) * 32, nb = (w >> 1) * 64;
  const int lo = l & 15, lg = l >> 4, lo7 = l & 7;
  const f32x4 fz = {0.f, 0.f, 0.f, 0.f};
  f32x4 acc[2][4];
#pragma unroll
  for (int i = 0; i < 2; ++i)
#pragma unroll
    for (int j = 0; j < 4; ++j) acc[i][j] = fz;

  const int g = tid;
  const int gr = g >> 3;
  const int gcsw = 8 * ((g & 7) ^ (gr & 7));
  const bf16* pa[2];
  const bf16* pb[4];
  bf16* la[2];
  bf16* lb[4];
#pragma unroll
  for (int s = 0; s < 2; ++s) {
    pa[s] = A + (long)(m0 + gr + 32 * s) * K + gcsw;
    la[s] = Ash + (g + 256 * s) * 8;
  }
#pragma unroll
  for (int s = 0; s < 4; ++s) {
    pb[s] = Bt + (long)(n0 + gr + 32 * s) * K + gcsw;
    lb[s] = Bsh + (g + 256 * s) * 8;
  }

  for (int k0 = 0; k0 < K; k0 += 64) {
    __syncthreads();
#pragma unroll
    for (int s = 0; s < 2; ++s) { gload16(pa[s], la[s]); pa[s] += 64; }
#pragma unroll
    for (int s = 0; s < 4; ++s) { gload16(pb[s], lb[s]); pb[s] += 64; }
    __syncthreads();
#pragma unroll
    for (int kk = 0; kk < 2; ++kk) {
      const int sl = ((kk * 4 + lg) ^ lo7) * 8;
      s16x8 a[2], b[4];
#pragma unroll
      for (int i = 0; i < 2; ++i)
        a[i] = *(const s16x8*)(Ash + (mb + i * 16 + lo) * 64 + sl);
#pragma unroll
      for (int j = 0; j < 4; ++j)
        b[j] = *(const s16x8*)(Bsh + (nb + j * 16 + lo) * 64 + sl);
#pragma unroll
      for (int i = 0; i < 2; ++i)
#pragma unroll
        for (int j = 0; j < 4; ++j)
          acc[i][j] = __builtin_amdgcn_mfma_f32_16x16x32_bf16(a[i], b[j], acc[i][j], 0, 0, 0);
    }
  }
  const int rb = m0 + mb + lg * 4;
  const int cb = n0 + nb + lo;
#pragma unroll
  for (int i = 0; i < 2; ++i) {
#pragma unroll
    for (int j = 0; j < 4; ++j) {
      const int col = cb + j * 16;
      float bv = 0.f;
      if (EPI >= 4) bv = bias[col];
#pragma unroll
      for (int r = 0; r < 4; ++r) {
        const int row = rb + i * 16 + r;
        const long idx = (long)row * ldc + col;
        float v = acc[i][j][r] + bv;
        if (EPI == 4) {
          v += ((const float*)res)[idx];
          ((bf16*)Cout)[idx] = __float2bfloat16(v);
        } else if (EPI == 5) {
          v += __bfloat162float(((const bf16*)res)[idx]);
          ((bf16*)Cout)[idx] = __float2bfloat16(v);
        } else if (EPI == 6) {
          v += __bfloat162float(((const bf16*)res)[idx]);
          ((float*)Cout)[idx] = v;
        } else {
          ((bf16*)Cout)[idx] = __float2bfloat16(v);
        }
      }
    }
  }
}

// ---------------- Flash self-attention v14: single pass, in-kernel normalize ----------------
__global__ __launch_bounds__(256, 3) void flash_kernel(const bf16* __restrict__ qkv,
                                                       const bf16* __restrict__ vT,
                                                       bf16* __restrict__ out) {
  __shared__ bf16 Ksh[64 * 80];
  __shared__ bf16 Vsh[80 * 64];
  const int bh = blockIdx.y, b = bh >> 3, h = bh & 7;
  const int tid = threadIdx.x, w = tid >> 6, l = tid & 63;
  const int r0 = blockIdx.x * 128 + w * 32;
  const int lg = l >> 4, lo = l & 15, lo7 = l & 7;
  const int sb = l & 48;
  const s16x8 sz = {0, 0, 0, 0, 0, 0, 0, 0};
  const f32x4 fz = {0.f, 0.f, 0.f, 0.f};

  s16x8 qa[2][3];
#pragma unroll
  for (int gq = 0; gq < 2; ++gq) {
    const bf16* qp = qkv + (long)(b * 4096 + r0 + gq * 16 + lo) * 1920 + h * 80;
    qa[gq][0] = *(const s16x8*)(qp + lg * 8);
    qa[gq][1] = *(const s16x8*)(qp + 32 + lg * 8);
    qa[gq][2] = (lg < 2) ? *(const s16x8*)(qp + 64 + lg * 8) : sz;
#pragma unroll
    for (int f = 0; f < 3; ++f) {
      s16x8 q = qa[gq][f], r;
#pragma unroll
      for (int i = 0; i < 8; ++i)
        r[i] = (short)(__bfloat16_as_ushort(__float2bfloat16(b2f(q[i]) * QSCALE)));
      qa[gq][f] = r;
    }
  }

  const bf16* kp[3];
  const int nbatch = (w < 2) ? 3 : 2;
#pragma unroll
  for (int it = 0; it < 3; ++it) {
    int g = tid + 256 * it;
    int gc = (g < 640) ? g : 0;
    int krow = gc / 10, ksl = gc % 10;
    int ksrc = (ksl < 8) ? (ksl ^ (krow & 7)) : (8 + ((ksl - 8) ^ ((krow >> 2) & 1)));
    kp[it] = qkv + (long)(b * 4096 + krow) * 1920 + 640 + h * 80 + ksrc * 8;
  }
  const bf16* vp0 = vT + (long)bh * 327680 + (long)(tid >> 3) * 4096 +
                    (((tid & 7) ^ ((tid >> 3) & 7)) * 8);
  const int soff0 = tid * 8;

  const int voff0 = (((lg >> 1) + 0) ^ lo7) * 8 + 4 * (lg & 1);
  const int voff1 = (((lg >> 1) + 2) ^ lo7) * 8 + 4 * (lg & 1);
  const int voff2 = (((lg >> 1) + 4) ^ lo7) * 8 + 4 * (lg & 1);
  const int voff3 = (((lg >> 1) + 6) ^ lo7) * 8 + 4 * (lg & 1);

  float lrA = 0.f, lrB = 0.f;
  f32x4 oA[5], oB[5];
#pragma unroll
  for (int dt = 0; dt < 5; ++dt) { oA[dt] = fz; oB[dt] = fz; }

#pragma unroll
  for (int it = 0; it < 3; ++it) {
    if (it < nbatch) {
      gload16(kp[it], Ksh + soff0 + 2048 * it); kp[it] += 64 * 1920;
      gload16(vp0 + (long)it * 131072, Vsh + soff0 + 2048 * it);
    }
  }
  __syncthreads();

  for (int kt = 0; kt < 64; ++kt) {
    unsigned paA[8], paB[8];
    f32x4 s0A, s0B, s1A, s1B;
    {
      s16x8 kb0 = *(const s16x8*)(Ksh + lo * 80 + ((lg ^ lo7)) * 8);
      s16x8 kb1 = *(const s16x8*)(Ksh + lo * 80 + (((4 + lg) ^ lo7)) * 8);
      s16x8 kb2 = (lg < 2) ? *(const s16x8*)(Ksh + lo * 80 + 64 + ((lg ^ ((lo >> 2) & 1))) * 8) : sz;
      __builtin_amdgcn_s_setprio(1);
      s0A = __builtin_amdgcn_mfma_f32_16x16x32_bf16(kb0, qa[0][0], fz, 0, 0, 0);
      s0A = __builtin_amdgcn_mfma_f32_16x16x32_bf16(kb1, qa[0][1], s0A, 0, 0, 0);
      s0A = __builtin_amdgcn_mfma_f32_16x16x32_bf16(kb2, qa[0][2], s0A, 0, 0, 0);
      s0B = __builtin_amdgcn_mfma_f32_16x16x32_bf16(kb0, qa[1][0], fz, 0, 0, 0);
      s0B = __builtin_amdgcn_mfma_f32_16x16x32_bf16(kb1, qa[1][1], s0B, 0, 0, 0);
      s0B = __builtin_amdgcn_mfma_f32_16x16x32_bf16(kb2, qa[1][2], s0B, 0, 0, 0);
      __builtin_amdgcn_s_setprio(0);
    }
#pragma unroll
    for (int ntl = 1; ntl <= 4; ++ntl) {
      if (ntl < 4) {
        s16x8 kb0 = *(const s16x8*)(Ksh + (ntl * 16 + lo) * 80 + ((lg ^ lo7)) * 8);
        s16x8 kb1 = *(const s16x8*)(Ksh + (ntl * 16 + lo) * 80 + (((4 + lg) ^ lo7)) * 8);
        s16x8 kb2 = (lg < 2)
                        ? *(const s16x8*)(Ksh + (ntl * 16 + lo) * 80 + 64 + ((lg ^ ((lo >> 2) & 1))) * 8)
                        : sz;
        __builtin_amdgcn_s_setprio(1);
        s1A = __builtin_amdgcn_mfma_f32_16x16x32_bf16(kb0, qa[0][0], fz, 0, 0, 0);
        s1A = __builtin_amdgcn_mfma_f32_16x16x32_bf16(kb1, qa[0][1], s1A, 0, 0, 0);
        s1A = __builtin_amdgcn_mfma_f32_16x16x32_bf16(kb2, qa[0][2], s1A, 0, 0, 0);
        s1B = __builtin_amdgcn_mfma_f32_16x16x32_bf16(kb0, qa[1][0], fz, 0, 0, 0);
        s1B = __builtin_amdgcn_mfma_f32_16x16x32_bf16(kb1, qa[1][1], s1B, 0, 0, 0);
        s1B = __builtin_amdgcn_mfma_f32_16x16x32_bf16(kb2, qa[1][2], s1B, 0, 0, 0);
        __builtin_amdgcn_s_setprio(0);
      }
      {
        const int pidx = ntl - 1;
        float a0 = __builtin_amdgcn_exp2f(s0A[0]);
        float a1 = __builtin_amdgcn_exp2f(s0A[1]);
        float a2 = __builtin_amdgcn_exp2f(s0A[2]);
        float a3 = __builtin_amdgcn_exp2f(s0A[3]);
        lrA += (a0 + a1) + (a2 + a3);
        unsigned u0, u1;
        asm("v_cvt_pk_bf16_f32 %0, %1, %2" : "=v"(u0) : "v"(a0), "v"(a1));
        asm("v_cvt_pk_bf16_f32 %0, %1, %2" : "=v"(u1) : "v"(a2), "v"(a3));
        paA[pidx * 2] = u0;
        paA[pidx * 2 + 1] = u1;
        float b0 = __builtin_amdgcn_exp2f(s0B[0]);
        float b1 = __builtin_amdgcn_exp2f(s0B[1]);
        float b2 = __builtin_amdgcn_exp2f(s0B[2]);
        float b3 = __builtin_amdgcn_exp2f(s0B[3]);
        lrB += (b0 + b1) + (b2 + b3);
        asm("v_cvt_pk_bf16_f32 %0, %1, %2" : "=v"(u0) : "v"(b0), "v"(b1));
        asm("v_cvt_pk_bf16_f32 %0, %1, %2" : "=v"(u1) : "v"(b2), "v"(b3));
        paB[pidx * 2] = u0;
        paB[pidx * 2 + 1] = u1;
      }
      s0A = s1A;
      s0B = s1B;
    }

    typedef unsigned u32x2 __attribute__((ext_vector_type(2)));
    s16x8 frA0, frA1, frB0, frB1;
    {
      u32x2* p;
      p = (u32x2*)&frA0; p[0] = (u32x2){paA[0], paA[1]}; p[1] = (u32x2){paA[2], paA[3]};
      p = (u32x2*)&frA1; p[0] = (u32x2){paA[4], paA[5]}; p[1] = (u32x2){paA[6], paA[7]};
      p = (u32x2*)&frB0; p[0] = (u32x2){paB[0], paB[1]}; p[1] = (u32x2){paB[2], paB[3]};
      p = (u32x2*)&frB1; p[0] = (u32x2){paB[4], paB[5]}; p[1] = (u32x2){paB[6], paB[7]};
    }

    __syncthreads();

    if (kt < 63) {
#pragma unroll
      for (int it = 0; it < 3; ++it) {
        if (it < nbatch) { gload16(kp[it], Ksh + soff0 + 2048 * it); kp[it] += 64 * 1920; }
      }
    }

    __builtin_amdgcn_s_setprio(1);
#pragma unroll
    for (int dt = 0; dt < 5; ++dt) {
      const bf16* vrow = Vsh + (dt * 16 + lo) * 64;
      s16x4 w00 = *(const s16x4*)(vrow + voff0);
      s16x4 w01 = *(const s16x4*)(vrow + voff1);
      s16x4 w10 = *(const s16x4*)(vrow + voff2);
      s16x4 w11 = *(const s16x4*)(vrow + voff3);
      s16x8 vb0 = __builtin_shufflevector(w00, w01, 0, 1, 2, 3, 4, 5, 6, 7);
      s16x8 vb1 = __builtin_shufflevector(w10, w11, 0, 1, 2, 3, 4, 5, 6, 7);
      oA[dt] = __builtin_amdgcn_mfma_f32_16x16x32_bf16(frA0, vb0, oA[dt], 0, 0, 0);
      oA[dt] = __builtin_amdgcn_mfma_f32_16x16x32_bf16(frA1, vb1, oA[dt], 0, 0, 0);
      oB[dt] = __builtin_amdgcn_mfma_f32_16x16x32_bf16(frB0, vb0, oB[dt], 0, 0, 0);
      oB[dt] = __builtin_amdgcn_mfma_f32_16x16x32_bf16(frB1, vb1, oB[dt], 0, 0, 0);
    }
    __builtin_amdgcn_s_setprio(0);

    __syncthreads();

    if (kt < 63) {
#pragma unroll
      for (int it = 0; it < 3; ++it) {
        if (it < nbatch) gload16(vp0 + (long)(kt + 1) * 64 + (long)it * 131072,
                                 Vsh + soff0 + 2048 * it);
      }
    }
  }

  {
    float ssum = lrA;
    ssum += __shfl_xor(ssum, 16);
    ssum += __shfl_xor(ssum, 32);
    const float linv = 1.f / ssum;
    float li[4];
#pragma unroll
    for (int r = 0; r < 4; ++r) li[r] = __shfl(linv, sb + lg * 4 + r);
    bf16* ob = out + (long)(b * 4096 + r0 + lg * 4) * 640 + h * 80 + lo;
#pragma unroll
    for (int r = 0; r < 4; ++r)
#pragma unroll
      for (int dt = 0; dt < 5; ++dt)
        ob[(long)r * 640 + dt * 16] = __float2bfloat16(oA[dt][r] * li[r]);
  }
  {
    float ssum = lrB;
    ssum += __shfl_xor(ssum, 16);
    ssum += __shfl_xor(ssum, 32);
    const float linv = 1.f / ssum;
    float li[4];
#pragma unroll
    for (int r = 0; r < 4; ++r) li[r] = __shfl(linv, sb + lg * 4 + r);
    bf16* ob = out + (long)(b * 4096 + r0 + 16 + lg * 4) * 640 + h * 80 + lo;
#pragma unroll
    for (int r = 0; r < 4; ++r)
#pragma unroll
      for (int dt = 0; dt < 5; ++dt)
        ob[(long)r * 640 + dt * 16] = __float2bfloat16(oB[dt][r] * li[r]);
  }
}

// ---------------- Cross-attention v2 (MFMA): 77 keys padded to 80, P in registers ----------------
__global__ __launch_bounds__(256) void cross_kernel(const bf16* __restrict__ q2,
                                                    const bf16* __restrict__ kv2,
                                                    bf16* __restrict__ out) {
  __shared__ bf16 Ksh2[80 * 88];
  __shared__ bf16 Vsh2[80 * 88];
  const int bh = blockIdx.y, b = bh >> 3, h = bh & 7;
  const int tid = threadIdx.x, w = tid >> 6, l = tid & 63;
  const int r0 = blockIdx.x * 128 + w * 32;
  const int lg = l >> 4, lo = l & 15;
  const int sb = l & 48;
  const s16x8 sz = {0, 0, 0, 0, 0, 0, 0, 0};
  const f32x4 fz = {0.f, 0.f, 0.f, 0.f};

  s16x8 qa[2][3];
#pragma unroll
  for (int gq = 0; gq < 2; ++gq) {
    const bf16* qp = q2 + (long)(b * 4096 + r0 + gq * 16 + lo) * 640 + h * 80;
    qa[gq][0] = *(const s16x8*)(qp + lg * 8);
    qa[gq][1] = *(const s16x8*)(qp + 32 + lg * 8);
    qa[gq][2] = (lg < 2) ? *(const s16x8*)(qp + 64 + lg * 8) : sz;
#pragma unroll
    for (int f = 0; f < 3; ++f) {
      s16x8 q = qa[gq][f], r;
#pragma unroll
      for (int i = 0; i < 8; ++i)
        r[i] = (short)(__bfloat16_as_ushort(__float2bfloat16(b2f(q[i]) * QSCALE)));
      qa[gq][f] = r;
    }
  }

  for (int c = tid; c < 800; c += 256) {
    int row = c / 10, s = c % 10;
    s16x8 v = sz;
    if (row < 77)
      v = *(const s16x8*)(kv2 + (long)(b * 77 + row) * 1280 + h * 80 + s * 8);
    *(s16x8*)(Ksh2 + row * 88 + s * 8) = v;
  }
  for (int c = tid; c < 770; c += 256) {
    int j = c / 10, d8 = (c % 10) * 8;
    s16x8 v = *(const s16x8*)(kv2 + (long)(b * 77 + j) * 1280 + 640 + h * 80 + d8);
    const short* vs = (const short*)&v;
#pragma unroll
    for (int i = 0; i < 8; ++i) ((short*)Vsh2)[(d8 + i) * 88 + j] = vs[i];
  }
  if (tid < 240) {
    int d = tid / 3, j = 77 + tid % 3;
    ((short*)Vsh2)[d * 88 + j] = 0;
  }
  __syncthreads();

  float lrA = 0.f, lrB = 0.f;
  f32x4 oA[5], oB[5];
#pragma unroll
  for (int dt = 0; dt < 5; ++dt) { oA[dt] = fz; oB[dt] = fz; }

  unsigned paA[10], paB[10];
  f32x4 s0A, s0B, s1A, s1B;
  {
    s16x8 kb0 = *(const s16x8*)(Ksh2 + lo * 88 + lg * 8);
    s16x8 kb1 = *(const s16x8*)(Ksh2 + lo * 88 + 32 + lg * 8);
    s16x8 kb2 = (lg < 2) ? *(const s16x8*)(Ksh2 + lo * 88 + 64 + lg * 8) : sz;
    __builtin_amdgcn_s_setprio(1);
    s0A = __builtin_amdgcn_mfma_f32_16x16x32_bf16(kb0, qa[0][0], fz, 0, 0, 0);
    s0A = __builtin_amdgcn_mfma_f32_16x16x32_bf16(kb1, qa[0][1], s0A, 0, 0, 0);
    s0A = __builtin_amdgcn_mfma_f32_16x16x32_bf16(kb2, qa[0][2], s0A, 0, 0, 0);
    s0B = __builtin_amdgcn_mfma_f32_16x16x32_bf16(kb0, qa[1][0], fz, 0, 0, 0);
    s0B = __builtin_amdgcn_mfma_f32_16x16x32_bf16(kb1, qa[1][1], s0B, 0, 0, 0);
    s0B = __builtin_amdgcn_mfma_f32_16x16x32_bf16(kb2, qa[1][2], s0B, 0, 0, 0);
    __builtin_amdgcn_s_setprio(0);
  }
#pragma unroll
  for (int ntl = 1; ntl <= 5; ++ntl) {
    if (ntl < 5) {
      s16x8 kb0 = *(const s16x8*)(Ksh2 + (ntl * 16 + lo) * 88 + lg * 8);
      s16x8 kb1 = *(const s16x8*)(Ksh2 + (ntl * 16 + lo) * 88 + 32 + lg * 8);
      s16x8 kb2 = (lg < 2) ? *(const s16x8*)(Ksh2 + (ntl * 16 + lo) * 88 + 64 + lg * 8) : sz;
      __builtin_amdgcn_s_setprio(1);
      s1A = __builtin_amdgcn_mfma_f32_16x16x32_bf16(kb0, qa[0][0], fz, 0, 0, 0);
      s1A = __builtin_amdgcn_mfma_f32_16x16x32_bf16(kb1, qa[0][1], s1A, 0, 0, 0);
      s1A = __builtin_amdgcn_mfma_f32_16x16x32_bf16(kb2, qa[0][2], s1A, 0, 0, 0);
      s1B = __builtin_amdgcn_mfma_f32_16x16x32_bf16(kb0, qa[1][0], fz, 0, 0, 0);
      s1B = __builtin_amdgcn_mfma_f32_16x16x32_bf16(kb1, qa[1][1], s1B, 0, 0, 0);
      s1B = __builtin_amdgcn_mfma_f32_16x16x32_bf16(kb2, qa[1][2], s1B, 0, 0, 0);
      __builtin_amdgcn_s_setprio(0);
    }
    {
      const int pidx = ntl - 1;
      float a0 = __builtin_amdgcn_exp2f(s0A[0]);
      float a1 = __builtin_amdgcn_exp2f(s0A[1]);
      float a2 = __builtin_amdgcn_exp2f(s0A[2]);
      float a3 = __builtin_amdgcn_exp2f(s0A[3]);
      float b0 = __builtin_amdgcn_exp2f(s0B[0]);
      float b1 = __builtin_amdgcn_exp2f(s0B[1]);
      float b2 = __builtin_amdgcn_exp2f(s0B[2]);
      float b3 = __builtin_amdgcn_exp2f(s0B[3]);
      if (pidx == 4) {
        if (lg * 4 + 1 >= 13) { a1 = 0.f; b1 = 0.f; }
        if (lg * 4 + 2 >= 13) { a2 = 0.f; b2 = 0.f; }
        if (lg * 4 + 3 >= 13) { a3 = 0.f; b3 = 0.f; }
      }
      lrA += (a0 + a1) + (a2 + a3);
      lrB += (b0 + b1) + (b2 + b3);
      unsigned u0, u1;
      asm("v_cvt_pk_bf16_f32 %0, %1, %2" : "=v"(u0) : "v"(a0), "v"(a1));
      asm("v_cvt_pk_bf16_f32 %0, %1, %2" : "=v"(u1) : "v"(a2), "v"(a3));
      paA[pidx * 2] = u0;
      paA[pidx * 2 + 1] = u1;
      asm("v_cvt_pk_bf16_f32 %0, %1, %2" : "=v"(u0) : "v"(b0), "v"(b1));
      asm("v_cvt_pk_bf16_f32 %0, %1, %2" : "=v"(u1) : "v"(b2), "v"(b3));
      paB[pidx * 2] = u0;
      paB[pidx * 2 + 1] = u1;
    }
    s0A = s1A;
    s0B = s1B;
  }

  typedef unsigned u32x2 __attribute__((ext_vector_type(2)));
  s16x8 frA0, frA1, frA2, frB0, frB1, frB2;
  {
    u32x2* p;
    p = (u32x2*)&frA0; p[0] = (u32x2){paA[0], paA[1]}; p[1] = (u32x2){paA[2], paA[3]};
    p = (u32x2*)&frA1; p[0] = (u32x2){paA[4], paA[5]}; p[1] = (u32x2){paA[6], paA[7]};
    p = (u32x2*)&frA2; p[0] = (u32x2){paA[8], paA[9]}; p[1] = (u32x2){0u, 0u};
    p = (u32x2*)&frB0; p[0] = (u32x2){paB[0], paB[1]}; p[1] = (u32x2){paB[2], paB[3]};
    p = (u32x2*)&frB1; p[0] = (u32x2){paB[4], paB[5]}; p[1] = (u32x2){paB[6], paB[7]};
    p = (u32x2*)&frB2; p[0] = (u32x2){paB[8], paB[9]}; p[1] = (u32x2){0u, 0u};
  }

  __builtin_amdgcn_s_setprio(1);
#pragma unroll
  for (int dt = 0; dt < 5; ++dt) {
    const bf16* vrow = Vsh2 + (dt * 16 + lo) * 88;
    s16x4 w00 = *(const s16x4*)(vrow + 4 * lg);
    s16x4 w01 = *(const s16x4*)(vrow + 16 + 4 * lg);
    s16x4 w10 = *(const s16x4*)(vrow + 32 + 4 * lg);
    s16x4 w11 = *(const s16x4*)(vrow + 48 + 4 * lg);
    s16x4 w20 = *(const s16x4*)(vrow + 64 + 4 * lg);
    s16x8 vb0 = __builtin_shufflevector(w00, w01, 0, 1, 2, 3, 4, 5, 6, 7);
    s16x8 vb1 = __builtin_shufflevector(w10, w11, 0, 1, 2, 3, 4, 5, 6, 7);
    s16x8 vb2 = __builtin_shufflevector(w20, w20, 0, 1, 2, 3, 0, 1, 2, 3);
    oA[dt] = __builtin_amdgcn_mfma_f32_16x16x32_bf16(frA0, vb0, oA[dt], 0, 0, 0);
    oA[dt] = __builtin_amdgcn_mfma_f32_16x16x32_bf16(frA1, vb1, oA[dt], 0, 0, 0);
    oA[dt] = __builtin_amdgcn_mfma_f32_16x16x32_bf16(frA2, vb2, oA[dt], 0, 0, 0);
    oB[dt] = __builtin_amdgcn_mfma_f32_16x16x32_bf16(frB0, vb0, oB[dt], 0, 0, 0);
    oB[dt] = __builtin_amdgcn_mfma_f32_16x16x32_bf16(frB1, vb1, oB[dt], 0, 0, 0);
    oB[dt] = __builtin_amdgcn_mfma_f32_16x16x32_bf16(frB2, vb2, oB[dt], 0, 0, 0);
  }
  __builtin_amdgcn_s_setprio(0);

  {
    float ssum = lrA;
    ssum += __shfl_xor(ssum, 16);
    ssum += __shfl_xor(ssum, 32);
    const float linv = 1.f / ssum;
    float li[4];
#pragma unroll
    for (int r = 0; r < 4; ++r) li[r] = __shfl(linv, sb + lg * 4 + r);
    bf16* ob = out + (long)(b * 4096 + r0 + lg * 4) * 640 + h * 80 + lo;
#pragma unroll
    for (int r = 0; r < 4; ++r)
#pragma unroll
      for (int dt = 0; dt < 5; ++dt)
        ob[(long)r * 640 + dt * 16] = __float2bfloat16(oA[dt][r] * li[r]);
  }
  {
    float ssum = lrB;
    ssum += __shfl_xor(ssum, 16);
    ssum += __shfl_xor(ssum, 32);
    const float linv = 1.f / ssum;
    float li[4];
#pragma unroll
    for (int r = 0; r < 4; ++r) li[r] = __shfl(linv, sb + lg * 4 + r);
    bf16* ob = out + (long)(b * 4096 + r0 + 16 + lg * 4) * 640 + h * 80 + lo;
#pragma unroll
    for (int r = 0; r < 4; ++r)
#pragma unroll
      for (int dt = 0; dt < 5; ++dt)
        ob[(long)r * 640 + dt * 16] = __float2bfloat16(oB[dt][r] * li[r]);
  }
}

// ---------------- FF1 + GEGLU fused v2: 256x64 tile (dual panel), BK=64, swizzled LDS ----------------
__global__ __launch_bounds__(256) void geglu_kernel(const bf16* __restrict__ A,
                                                    const bf16* __restrict__ Bt,
                                                    const float* __restrict__ bias,
                                                    bf16* __restrict__ Cout) {
  __shared__ bf16 Ash[256 * 64];
  __shared__ bf16 Bsh[2][64 * 64];
  const int tid = threadIdx.x, w = tid >> 6, l = tid & 63;
  const int m0 = blockIdx.x * 256, n0 = blockIdx.y * 64;
  const int lo = l & 15, lg = l >> 4, lo7 = l & 7;
  const int mb = w * 64;
  const f32x4 fz = {0.f, 0.f, 0.f, 0.f};
  f32x4 accA[4][4], accG[4][4];
#pragma unroll
  for (int i = 0; i < 4; ++i)
#pragma unroll
    for (int j = 0; j < 4; ++j) { accA[i][j] = fz; accG[i][j] = fz; }

  const int g = tid;
  const int gr = g >> 3;
  const int gcsw = 8 * ((g & 7) ^ (gr & 7));
  const bf16* pa[8];
  const bf16* pb[2][2];
  bf16* la[8];
  bf16* lb[2][2];
#pragma unroll
  for (int s = 0; s < 8; ++s) {
    pa[s] = A + (long)(m0 + gr + 32 * s) * 640 + gcsw;
    la[s] = Ash + (g + 256 * s) * 8;
  }
#pragma unroll
  for (int q = 0; q < 2; ++q)
#pragma unroll
    for (int s = 0; s < 2; ++s) {
      pb[q][s] = Bt + (long)(n0 + q * 2560 + gr + 32 * s) * 640 + gcsw;
      lb[q][s] = Bsh[q] + (g + 256 * s) * 8;
    }

  for (int k0 = 0; k0 < 640; k0 += 64) {
    __syncthreads();
#pragma unroll
    for (int s = 0; s < 8; ++s) { gload16(pa[s], la[s]); pa[s] += 64; }
#pragma unroll
    for (int q = 0; q < 2; ++q)
#pragma unroll
      for (int s = 0; s < 2; ++s) { gload16(pb[q][s], lb[q][s]); pb[q][s] += 64; }
    __syncthreads();
#pragma unroll
    for (int kk = 0; kk < 2; ++kk) {
      const int sl = ((kk * 4 + lg) ^ lo7) * 8;
      s16x8 a[4], ba[4], bg[4];
#pragma unroll
      for (int i = 0; i < 4; ++i)
        a[i] = *(const s16x8*)(Ash + (mb + i * 16 + lo) * 64 + sl);
#pragma unroll
      for (int j = 0; j < 4; ++j) {
        ba[j] = *(const s16x8*)(Bsh[0] + (j * 16 + lo) * 64 + sl);
        bg[j] = *(const s16x8*)(Bsh[1] + (j * 16 + lo) * 64 + sl);
      }
#pragma unroll
      for (int i = 0; i < 4; ++i)
#pragma unroll
        for (int j = 0; j < 4; ++j) {
          accA[i][j] = __builtin_amdgcn_mfma_f32_16x16x32_bf16(a[i], ba[j], accA[i][j], 0, 0, 0);
          accG[i][j] = __builtin_amdgcn_mfma_f32_16x16x32_bf16(a[i], bg[j], accG[i][j], 0, 0, 0);
        }
    }
  }
#pragma unroll
  for (int i = 0; i < 4; ++i) {
#pragma unroll
    for (int j = 0; j < 4; ++j) {
      const int col = n0 + j * 16 + lo;
      const float bA = bias[col];
      const float bG = bias[2560 + col];
#pragma unroll
      for (int r = 0; r < 4; ++r) {
        const long row = m0 + mb + i * 16 + lg * 4 + r;
        const float av = accA[i][j][r] + bA;
        const float gv = accG[i][j][r] + bG;
        const float ge = 0.5f * gv * (1.f + erff(gv * 0.70710678118654752f));
        Cout[row * 2560 + col] = __float2bfloat16(av * ge);
      }
    }
  }
}

// ---------------- host launch ----------------
extern "C" void kernel_launch(void* const* d_in, const int* in_sizes, int n_in,
                              void* d_out, int out_size, void* d_ws, size_t ws_size,
                              hipStream_t stream) {
  (void)in_sizes; (void)n_in; (void)out_size; (void)ws_size;
  const float* x    = (const float*)d_in[0];
  const float* ctx  = (const float*)d_in[1];
  const float* ln1w = (const float*)d_in[2];
  const float* ln1b = (const float*)d_in[3];
  const float* ln2w = (const float*)d_in[4];
  const float* ln2b = (const float*)d_in[5];
  const float* ln3w = (const float*)d_in[6];
  const float* ln3b = (const float*)d_in[7];
  const float* wq1  = (const float*)d_in[8];
  const float* wk1  = (const float*)d_in[9];
  const float* wv1  = (const float*)d_in[10];
  const float* wo1  = (const float*)d_in[11];
  const float* bo1  = (const float*)d_in[12];
  const float* wq2  = (const float*)d_in[13];
  const float* wk2  = (const float*)d_in[14];
  const float* wv2  = (const float*)d_in[15];
  const float* wo2  = (const float*)d_in[16];
  const float* bo2  = (const float*)d_in[17];
  const float* wff1 = (const float*)d_in[18];
  const float* bff1 = (const float*)d_in[19];
  const float* wff2 = (const float*)d_in[20];
  const float* bff2 = (const float*)d_in[21];

  char* ws = (char*)d_ws;
  bf16* Wqkv1 = (bf16*)(ws + 0);           // [1920][640]
  bf16* Wo1t  = (bf16*)(ws + 2457600);     // [640][640]
  bf16* Wq2t  = (bf16*)(ws + 3276800);     // [640][640]
  bf16* Wkv2t = (bf16*)(ws + 4096000);     // [1280][768]
  bf16* Wo2t  = (bf16*)(ws + 6062080);     // [640][640]
  bf16* Wff1t = (bf16*)(ws + 6881280);     // [5120][640]
  bf16* Wff2t = (bf16*)(ws + 13434880);    // [640][2560]
  bf16* Ctxb  = (bf16*)(ws + 16711680);    // [154][768]
  bf16* Hln   = (bf16*)(ws + 16948224);    // [8192][640]
  bf16* X2b   = (bf16*)(ws + 27433984);    // [8192][640] bf16 residual
  bf16* X3b   = (bf16*)(ws + 48405504);    // [8192][640] bf16 residual
  bf16* Qkv   = (bf16*)(ws + 69377024);    // [8192][1920]
  bf16* Ffin  = Qkv;                       // reuse: [8192][2560]
  bf16* Vt    = (bf16*)(ws + 100834304);   // [16][80][4096]
  bf16* Ao    = (bf16*)(ws + 111320064);   // [8192][640]
  bf16* Q2    = (bf16*)(ws + 121805824);   // [8192][640]
  bf16* Kv2   = (bf16*)(ws + 132291584);   // [154][1280]
  float* Outf = (float*)d_out;

  dim3 blk(256);

  // fused weight prep: one launch for all transposes + ctx cvt
  PrepArgs pa;
  const float* srcs[10] = {wq1, wk1, wv1, wo1, wq2, wk2, wv2, wo2, wff1, wff2};
  bf16* dsts[10] = {Wqkv1, Wqkv1 + 640 * 640, Wqkv1 + 2 * 640 * 640, Wo1t, Wq2t,
                    Wkv2t, Wkv2t + 640 * 768, Wo2t, Wff1t, Wff2t};
  int Rs[10] = {640, 640, 640, 640, 640, 768, 768, 640, 640, 2560};
  int Cs[10] = {640, 640, 640, 640, 640, 640, 640, 640, 5120, 640};
  int baseacc = 0;
  for (int j = 0; j < 10; ++j) {
    pa.src[j] = srcs[j];
    pa.dst[j] = dsts[j];
    pa.R[j] = Rs[j];
    pa.C[j] = Cs[j];
    pa.cb[j] = Cs[j] / 32;
    pa.base[j] = baseacc;
    baseacc += (Cs[j] / 32) * (Rs[j] / 32);
  }
  pa.cvtbase = baseacc;            // 8160
  pa.ctx = ctx;
  pa.ctxb = Ctxb;
  const int prep_blocks = baseacc + 116;
  prep_kernel<<<prep_blocks, blk, 0, stream>>>(pa);

  // self-attention block (QKV GEMM writes V transposed directly into Vt)
  ln_kernel<float><<<2048, blk, 0, stream>>>(x, ln1w, ln1b, Hln);
  gemm_kernel<3><<<dim3(64, 15), blk, 0, stream>>>(Hln, Wqkv1, nullptr, (const float*)Vt, Qkv, 8192, 640, 1920);
  flash_kernel<<<dim3(32, 16), blk, 0, stream>>>(Qkv, Vt, Ao);
  gemm64_kernel<4><<<dim3(128, 5), blk, 0, stream>>>(Ao, Wo1t, bo1, x, X2b, 640, 640);
  // cross-attention block
  ln_kernel<bf16><<<2048, blk, 0, stream>>>(X2b, ln2w, ln2b, Hln);
  gemm64_kernel<0><<<dim3(128, 5), blk, 0, stream>>>(Hln, Wq2t, nullptr, nullptr, Q2, 640, 640);
  gemm_kernel<0><<<dim3(2, 10), blk, 0, stream>>>(Ctxb, Wkv2t, nullptr, nullptr, Kv2, 154, 768, 1280);
  cross_kernel<<<dim3(32, 16), blk, 0, stream>>>(Q2, Kv2, Ao);
  gemm64_kernel<5><<<dim3(128, 5), blk, 0, stream>>>(Ao, Wo2t, bo2, X2b, X3b, 640, 640);
  // GEGLU FF block
  ln_kernel<bf16><<<2048, blk, 0, stream>>>(X3b, ln3w, ln3b, Hln);
  geglu_kernel<<<dim3(32, 40), blk, 0, stream>>>(Hln, Wff1t, bff1, Ffin);
  gemm64_kernel<6><<<dim3(128, 5), blk, 0, stream>>>(Ffin, Wff2t, bff2, X3b, Outf, 2560, 640);
}

// Round 17
// 344.958 us; speedup vs baseline: 1.1448x; 1.1448x over previous
//
#include <hip/hip_runtime.h>
#include <hip/hip_bf16.h>

typedef __hip_bfloat16 bf16;
typedef short s16x8 __attribute__((ext_vector_type(8)));
typedef short s16x4 __attribute__((ext_vector_type(4)));
typedef float f32x4 __attribute__((ext_vector_type(4)));

#define SCALE_DH 0.11180339887498949f   // 80^-0.5
#define QSCALE   0.16129820878f         // 80^-0.5 * log2(e)

static __device__ __forceinline__ float b2f(short u) {
  union { float f; unsigned int i; } x;
  x.i = ((unsigned int)(unsigned short)u) << 16;
  return x.f;
}

static __device__ __forceinline__ float tof(float x) { return x; }
static __device__ __forceinline__ float tof(bf16 x) { return __bfloat162float(x); }

static __device__ __forceinline__ void gload16(const bf16* g, bf16* l) {
  __builtin_amdgcn_global_load_lds((__attribute__((address_space(1))) const void*)g,
                                   (__attribute__((address_space(3))) void*)l, 16, 0, 0);
}

// ---------------- fused weight prep: 10 transposes + 1 cvt in one launch ----------------
struct PrepArgs {
  const float* src[10];
  bf16* dst[10];
  int R[10], C[10], cb[10], base[10];
  int cvtbase;
  const float* ctx;
  bf16* ctxb;
};

__global__ __launch_bounds__(256) void prep_kernel(PrepArgs a) {
  const int bid = blockIdx.x;
  if (bid >= a.cvtbase) {
    const int n = 154 * 768;
    int i = ((bid - a.cvtbase) * 256 + threadIdx.x) * 4;
    if (i + 4 <= n) {
      float4 v = *(const float4*)(a.ctx + i);
      a.ctxb[i + 0] = __float2bfloat16(v.x);
      a.ctxb[i + 1] = __float2bfloat16(v.y);
      a.ctxb[i + 2] = __float2bfloat16(v.z);
      a.ctxb[i + 3] = __float2bfloat16(v.w);
    } else {
      for (int k = i; k < n; ++k) a.ctxb[k] = __float2bfloat16(a.ctx[k]);
    }
    return;
  }
  int jid = 0;
#pragma unroll
  for (int k = 1; k < 10; ++k)
    if (bid >= a.base[k]) jid = k;
  const float* in = a.src[jid];
  bf16* out = a.dst[jid];
  const int R = a.R[jid], C = a.C[jid];
  const int lb = bid - a.base[jid];
  const int cblk = lb % a.cb[jid], rblk = lb / a.cb[jid];
  __shared__ float t[32][33];
  const int tx = threadIdx.x & 31, ty = threadIdx.x >> 5;
  const long r0 = (long)rblk * 32, c0 = (long)cblk * 32;
#pragma unroll
  for (int i = 0; i < 4; ++i)
    t[ty + 8 * i][tx] = in[(r0 + ty + 8 * i) * C + c0 + tx];
  __syncthreads();
#pragma unroll
  for (int i = 0; i < 4; ++i)
    out[(c0 + ty + 8 * i) * R + r0 + tx] = __float2bfloat16(t[tx][ty + 8 * i]);
}

// ---------------- LayerNorm D=640: T in -> bf16 out (one wave per row) ----------------
template <typename T>
__global__ __launch_bounds__(256) void ln_kernel(const T* __restrict__ x,
                                                 const float* __restrict__ w,
                                                 const float* __restrict__ b,
                                                 bf16* __restrict__ out) {
  const int wv = threadIdx.x >> 6, l = threadIdx.x & 63;
  const long row = (long)blockIdx.x * 4 + wv;
  const T* xr = x + row * 640;
  float v[10];
  float s = 0.f;
#pragma unroll
  for (int j = 0; j < 10; ++j) { v[j] = tof(xr[l + 64 * j]); s += v[j]; }
#pragma unroll
  for (int o = 32; o > 0; o >>= 1) s += __shfl_xor(s, o);
  const float mean = s * (1.f / 640.f);
  float vs = 0.f;
#pragma unroll
  for (int j = 0; j < 10; ++j) { float d = v[j] - mean; vs += d * d; }
#pragma unroll
  for (int o = 32; o > 0; o >>= 1) vs += __shfl_xor(vs, o);
  const float rstd = rsqrtf(vs * (1.f / 640.f) + 1e-5f);
  bf16* orow = out + row * 640;
#pragma unroll
  for (int j = 0; j < 10; ++j) {
    int d = l + 64 * j;
    orow[d] = __float2bfloat16((v[j] - mean) * rstd * w[d] + b[d]);
  }
}

// ---------------- GEMM 128x128: C[M,N] = A[M,K](bf16) * W, Bt = W^T [N][K] ----------------
// EPI 0: bf16 out. EPI 3 (QKV): bf16 out for col<1280; V cols written TRANSPOSED to vt (res param).
template <int EPI>
__global__ __launch_bounds__(256) void gemm_kernel(const bf16* __restrict__ A,
                                                   const bf16* __restrict__ Bt,
                                                   const float* __restrict__ bias,
                                                   const float* __restrict__ res,
                                                   void* __restrict__ Cout,
                                                   int M, int K, int ldc) {
  __shared__ bf16 Ash[128 * 64];
  __shared__ bf16 Bsh[128 * 64];
  const int tid = threadIdx.x, w = tid >> 6, l = tid & 63;
  const int m0 = blockIdx.x * 128, n0 = blockIdx.y * 128;
  const int mb = (w >> 1) * 64, nb = (w & 1) * 64;
  const int lo = l & 15, lg = l >> 4, lo7 = l & 7;
  const f32x4 fz = {0.f, 0.f, 0.f, 0.f};
  f32x4 acc[4][4];
#pragma unroll
  for (int i = 0; i < 4; ++i)
#pragma unroll
    for (int j = 0; j < 4; ++j) acc[i][j] = fz;

  const int g = tid;
  const int gr = g >> 3;
  const int gcsw = 8 * ((g & 7) ^ (gr & 7));
  const bf16* pa[4];
  const bf16* pb[4];
  bf16* la[4];
  bf16* lb[4];
#pragma unroll
  for (int s = 0; s < 4; ++s) {
    const int rl = gr + 32 * s;
    int ra = m0 + rl; if (ra >= M) ra = M - 1;
    pa[s] = A + (long)ra * K + gcsw;
    pb[s] = Bt + (long)(n0 + rl) * K + gcsw;
    la[s] = Ash + (g + 256 * s) * 8;
    lb[s] = Bsh + (g + 256 * s) * 8;
  }

  for (int k0 = 0; k0 < K; k0 += 64) {
    __syncthreads();
#pragma unroll
    for (int s = 0; s < 4; ++s) {
      gload16(pa[s], la[s]); pa[s] += 64;
      gload16(pb[s], lb[s]); pb[s] += 64;
    }
    __syncthreads();
#pragma unroll
    for (int kk = 0; kk < 2; ++kk) {
      const int sl = ((kk * 4 + lg) ^ lo7) * 8;
      s16x8 a[4], b[4];
#pragma unroll
      for (int i = 0; i < 4; ++i)
        a[i] = *(const s16x8*)(Ash + (mb + i * 16 + lo) * 64 + sl);
#pragma unroll
      for (int j = 0; j < 4; ++j)
        b[j] = *(const s16x8*)(Bsh + (nb + j * 16 + lo) * 64 + sl);
#pragma unroll
      for (int i = 0; i < 4; ++i)
#pragma unroll
        for (int j = 0; j < 4; ++j)
          acc[i][j] = __builtin_amdgcn_mfma_f32_16x16x32_bf16(a[i], b[j], acc[i][j], 0, 0, 0);
    }
  }
  const int rb = m0 + mb + lg * 4;
  const int cb = n0 + nb + lo;
#pragma unroll
  for (int i = 0; i < 4; ++i) {
#pragma unroll
    for (int j = 0; j < 4; ++j) {
      const int col = cb + j * 16;
      if (EPI == 3 && col >= 1280) {
        const int t = col - 1280;
        const int hh = t / 80, dh = t % 80;
        const int row0 = rb + i * 16;
        const int bb = row0 >> 12, n = row0 & 4095;
        s16x4 pk;
#pragma unroll
        for (int r = 0; r < 4; ++r)
          pk[r] = (short)__bfloat16_as_ushort(__float2bfloat16(acc[i][j][r]));
        bf16* vt = (bf16*)res;
        *(s16x4*)(vt + (long)(bb * 8 + hh) * 327680 + (long)dh * 4096 + n) = pk;
        continue;
      }
#pragma unroll
      for (int r = 0; r < 4; ++r) {
        const int row = rb + i * 16 + r;
        if (row < M)
          ((bf16*)Cout)[(long)row * ldc + col] = __float2bfloat16(acc[i][j][r]);
      }
    }
  }
}

// ---------------- GEMM 64x128 (N=640 GEMMs; M % 64 == 0) ----------------
// EPI 0: bf16 out, no bias. EPI 4: bf16 out = acc+bias+f32 res. EPI 5: bf16 out = acc+bias+bf16 res.
// EPI 6: f32 out = acc+bias+bf16 res.
template <int EPI>
__global__ __launch_bounds__(256) void gemm64_kernel(const bf16* __restrict__ A,
                                                     const bf16* __restrict__ Bt,
                                                     const float* __restrict__ bias,
                                                     const void* __restrict__ res,
                                                     void* __restrict__ Cout,
                                                     int K, int ldc) {
  __shared__ bf16 Ash[64 * 64];
  __shared__ bf16 Bsh[128 * 64];
  const int tid = threadIdx.x, w = tid >> 6, l = tid & 63;
  const int m0 = blockIdx.x * 64, n0 = blockIdx.y * 128;
  const int mb = (w & 1) * 32, nb = (w >> 1) * 64;
  const int lo = l & 15, lg = l >> 4, lo7 = l & 7;
  const f32x4 fz = {0.f, 0.f, 0.f, 0.f};
  f32x4 acc[2][4];
#pragma unroll
  for (int i = 0; i < 2; ++i)
#pragma unroll
    for (int j = 0; j < 4; ++j) acc[i][j] = fz;

  const int g = tid;
  const int gr = g >> 3;
  const int gcsw = 8 * ((g & 7) ^ (gr & 7));
  const bf16* pa[2];
  const bf16* pb[4];
  bf16* la[2];
  bf16* lb[4];
#pragma unroll
  for (int s = 0; s < 2; ++s) {
    pa[s] = A + (long)(m0 + gr + 32 * s) * K + gcsw;
    la[s] = Ash + (g + 256 * s) * 8;
  }
#pragma unroll
  for (int s = 0; s < 4; ++s) {
    pb[s] = Bt + (long)(n0 + gr + 32 * s) * K + gcsw;
    lb[s] = Bsh + (g + 256 * s) * 8;
  }

  for (int k0 = 0; k0 < K; k0 += 64) {
    __syncthreads();
#pragma unroll
    for (int s = 0; s < 2; ++s) { gload16(pa[s], la[s]); pa[s] += 64; }
#pragma unroll
    for (int s = 0; s < 4; ++s) { gload16(pb[s], lb[s]); pb[s] += 64; }
    __syncthreads();
#pragma unroll
    for (int kk = 0; kk < 2; ++kk) {
      const int sl = ((kk * 4 + lg) ^ lo7) * 8;
      s16x8 a[2], b[4];
#pragma unroll
      for (int i = 0; i < 2; ++i)
        a[i] = *(const s16x8*)(Ash + (mb + i * 16 + lo) * 64 + sl);
#pragma unroll
      for (int j = 0; j < 4; ++j)
        b[j] = *(const s16x8*)(Bsh + (nb + j * 16 + lo) * 64 + sl);
#pragma unroll
      for (int i = 0; i < 2; ++i)
#pragma unroll
        for (int j = 0; j < 4; ++j)
          acc[i][j] = __builtin_amdgcn_mfma_f32_16x16x32_bf16(a[i], b[j], acc[i][j], 0, 0, 0);
    }
  }
  const int rb = m0 + mb + lg * 4;
  const int cb = n0 + nb + lo;
#pragma unroll
  for (int i = 0; i < 2; ++i) {
#pragma unroll
    for (int j = 0; j < 4; ++j) {
      const int col = cb + j * 16;
      float bv = 0.f;
      if (EPI >= 4) bv = bias[col];
#pragma unroll
      for (int r = 0; r < 4; ++r) {
        const int row = rb + i * 16 + r;
        const long idx = (long)row * ldc + col;
        float v = acc[i][j][r] + bv;
        if (EPI == 4) {
          v += ((const float*)res)[idx];
          ((bf16*)Cout)[idx] = __float2bfloat16(v);
        } else if (EPI == 5) {
          v += __bfloat162float(((const bf16*)res)[idx]);
          ((bf16*)Cout)[idx] = __float2bfloat16(v);
        } else if (EPI == 6) {
          v += __bfloat162float(((const bf16*)res)[idx]);
          ((float*)Cout)[idx] = v;
        } else {
          ((bf16*)Cout)[idx] = __float2bfloat16(v);
        }
      }
    }
  }
}

// ---------------- Flash self-attention v14: single pass, in-kernel normalize ----------------
__global__ __launch_bounds__(256, 3) void flash_kernel(const bf16* __restrict__ qkv,
                                                       const bf16* __restrict__ vT,
                                                       bf16* __restrict__ out) {
  __shared__ bf16 Ksh[64 * 80];
  __shared__ bf16 Vsh[80 * 64];
  const int bh = blockIdx.y, b = bh >> 3, h = bh & 7;
  const int tid = threadIdx.x, w = tid >> 6, l = tid & 63;
  const int r0 = blockIdx.x * 128 + w * 32;
  const int lg = l >> 4, lo = l & 15, lo7 = l & 7;
  const int sb = l & 48;
  const s16x8 sz = {0, 0, 0, 0, 0, 0, 0, 0};
  const f32x4 fz = {0.f, 0.f, 0.f, 0.f};

  s16x8 qa[2][3];
#pragma unroll
  for (int gq = 0; gq < 2; ++gq) {
    const bf16* qp = qkv + (long)(b * 4096 + r0 + gq * 16 + lo) * 1920 + h * 80;
    qa[gq][0] = *(const s16x8*)(qp + lg * 8);
    qa[gq][1] = *(const s16x8*)(qp + 32 + lg * 8);
    qa[gq][2] = (lg < 2) ? *(const s16x8*)(qp + 64 + lg * 8) : sz;
#pragma unroll
    for (int f = 0; f < 3; ++f) {
      s16x8 q = qa[gq][f], r;
#pragma unroll
      for (int i = 0; i < 8; ++i)
        r[i] = (short)(__bfloat16_as_ushort(__float2bfloat16(b2f(q[i]) * QSCALE)));
      qa[gq][f] = r;
    }
  }

  const bf16* kp[3];
  const int nbatch = (w < 2) ? 3 : 2;
#pragma unroll
  for (int it = 0; it < 3; ++it) {
    int g = tid + 256 * it;
    int gc = (g < 640) ? g : 0;
    int krow = gc / 10, ksl = gc % 10;
    int ksrc = (ksl < 8) ? (ksl ^ (krow & 7)) : (8 + ((ksl - 8) ^ ((krow >> 2) & 1)));
    kp[it] = qkv + (long)(b * 4096 + krow) * 1920 + 640 + h * 80 + ksrc * 8;
  }
  const bf16* vp0 = vT + (long)bh * 327680 + (long)(tid >> 3) * 4096 +
                    (((tid & 7) ^ ((tid >> 3) & 7)) * 8);
  const int soff0 = tid * 8;

  const int voff0 = (((lg >> 1) + 0) ^ lo7) * 8 + 4 * (lg & 1);
  const int voff1 = (((lg >> 1) + 2) ^ lo7) * 8 + 4 * (lg & 1);
  const int voff2 = (((lg >> 1) + 4) ^ lo7) * 8 + 4 * (lg & 1);
  const int voff3 = (((lg >> 1) + 6) ^ lo7) * 8 + 4 * (lg & 1);

  float lrA = 0.f, lrB = 0.f;
  f32x4 oA[5], oB[5];
#pragma unroll
  for (int dt = 0; dt < 5; ++dt) { oA[dt] = fz; oB[dt] = fz; }

#pragma unroll
  for (int it = 0; it < 3; ++it) {
    if (it < nbatch) {
      gload16(kp[it], Ksh + soff0 + 2048 * it); kp[it] += 64 * 1920;
      gload16(vp0 + (long)it * 131072, Vsh + soff0 + 2048 * it);
    }
  }
  __syncthreads();

  for (int kt = 0; kt < 64; ++kt) {
    unsigned paA[8], paB[8];
    f32x4 s0A, s0B, s1A, s1B;
    {
      s16x8 kb0 = *(const s16x8*)(Ksh + lo * 80 + ((lg ^ lo7)) * 8);
      s16x8 kb1 = *(const s16x8*)(Ksh + lo * 80 + (((4 + lg) ^ lo7)) * 8);
      s16x8 kb2 = (lg < 2) ? *(const s16x8*)(Ksh + lo * 80 + 64 + ((lg ^ ((lo >> 2) & 1))) * 8) : sz;
      __builtin_amdgcn_s_setprio(1);
      s0A = __builtin_amdgcn_mfma_f32_16x16x32_bf16(kb0, qa[0][0], fz, 0, 0, 0);
      s0A = __builtin_amdgcn_mfma_f32_16x16x32_bf16(kb1, qa[0][1], s0A, 0, 0, 0);
      s0A = __builtin_amdgcn_mfma_f32_16x16x32_bf16(kb2, qa[0][2], s0A, 0, 0, 0);
      s0B = __builtin_amdgcn_mfma_f32_16x16x32_bf16(kb0, qa[1][0], fz, 0, 0, 0);
      s0B = __builtin_amdgcn_mfma_f32_16x16x32_bf16(kb1, qa[1][1], s0B, 0, 0, 0);
      s0B = __builtin_amdgcn_mfma_f32_16x16x32_bf16(kb2, qa[1][2], s0B, 0, 0, 0);
      __builtin_amdgcn_s_setprio(0);
    }
#pragma unroll
    for (int ntl = 1; ntl <= 4; ++ntl) {
      if (ntl < 4) {
        s16x8 kb0 = *(const s16x8*)(Ksh + (ntl * 16 + lo) * 80 + ((lg ^ lo7)) * 8);
        s16x8 kb1 = *(const s16x8*)(Ksh + (ntl * 16 + lo) * 80 + (((4 + lg) ^ lo7)) * 8);
        s16x8 kb2 = (lg < 2)
                        ? *(const s16x8*)(Ksh + (ntl * 16 + lo) * 80 + 64 + ((lg ^ ((lo >> 2) & 1))) * 8)
                        : sz;
        __builtin_amdgcn_s_setprio(1);
        s1A = __builtin_amdgcn_mfma_f32_16x16x32_bf16(kb0, qa[0][0], fz, 0, 0, 0);
        s1A = __builtin_amdgcn_mfma_f32_16x16x32_bf16(kb1, qa[0][1], s1A, 0, 0, 0);
        s1A = __builtin_amdgcn_mfma_f32_16x16x32_bf16(kb2, qa[0][2], s1A, 0, 0, 0);
        s1B = __builtin_amdgcn_mfma_f32_16x16x32_bf16(kb0, qa[1][0], fz, 0, 0, 0);
        s1B = __builtin_amdgcn_mfma_f32_16x16x32_bf16(kb1, qa[1][1], s1B, 0, 0, 0);
        s1B = __builtin_amdgcn_mfma_f32_16x16x32_bf16(kb2, qa[1][2], s1B, 0, 0, 0);
        __builtin_amdgcn_s_setprio(0);
      }
      {
        const int pidx = ntl - 1;
        float a0 = __builtin_amdgcn_exp2f(s0A[0]);
        float a1 = __builtin_amdgcn_exp2f(s0A[1]);
        float a2 = __builtin_amdgcn_exp2f(s0A[2]);
        float a3 = __builtin_amdgcn_exp2f(s0A[3]);
        lrA += (a0 + a1) + (a2 + a3);
        unsigned u0, u1;
        asm("v_cvt_pk_bf16_f32 %0, %1, %2" : "=v"(u0) : "v"(a0), "v"(a1));
        asm("v_cvt_pk_bf16_f32 %0, %1, %2" : "=v"(u1) : "v"(a2), "v"(a3));
        paA[pidx * 2] = u0;
        paA[pidx * 2 + 1] = u1;
        float b0 = __builtin_amdgcn_exp2f(s0B[0]);
        float b1 = __builtin_amdgcn_exp2f(s0B[1]);
        float b2 = __builtin_amdgcn_exp2f(s0B[2]);
        float b3 = __builtin_amdgcn_exp2f(s0B[3]);
        lrB += (b0 + b1) + (b2 + b3);
        asm("v_cvt_pk_bf16_f32 %0, %1, %2" : "=v"(u0) : "v"(b0), "v"(b1));
        asm("v_cvt_pk_bf16_f32 %0, %1, %2" : "=v"(u1) : "v"(b2), "v"(b3));
        paB[pidx * 2] = u0;
        paB[pidx * 2 + 1] = u1;
      }
      s0A = s1A;
      s0B = s1B;
    }

    typedef unsigned u32x2 __attribute__((ext_vector_type(2)));
    s16x8 frA0, frA1, frB0, frB1;
    {
      u32x2* p;
      p = (u32x2*)&frA0; p[0] = (u32x2){paA[0], paA[1]}; p[1] = (u32x2){paA[2], paA[3]};
      p = (u32x2*)&frA1; p[0] = (u32x2){paA[4], paA[5]}; p[1] = (u32x2){paA[6], paA[7]};
      p = (u32x2*)&frB0; p[0] = (u32x2){paB[0], paB[1]}; p[1] = (u32x2){paB[2], paB[3]};
      p = (u32x2*)&frB1; p[0] = (u32x2){paB[4], paB[5]}; p[1] = (u32x2){paB[6], paB[7]};
    }

    __syncthreads();

    if (kt < 63) {
#pragma unroll
      for (int it = 0; it < 3; ++it) {
        if (it < nbatch) { gload16(kp[it], Ksh + soff0 + 2048 * it); kp[it] += 64 * 1920; }
      }
    }

    __builtin_amdgcn_s_setprio(1);
#pragma unroll
    for (int dt = 0; dt < 5; ++dt) {
      const bf16* vrow = Vsh + (dt * 16 + lo) * 64;
      s16x4 w00 = *(const s16x4*)(vrow + voff0);
      s16x4 w01 = *(const s16x4*)(vrow + voff1);
      s16x4 w10 = *(const s16x4*)(vrow + voff2);
      s16x4 w11 = *(const s16x4*)(vrow + voff3);
      s16x8 vb0 = __builtin_shufflevector(w00, w01, 0, 1, 2, 3, 4, 5, 6, 7);
      s16x8 vb1 = __builtin_shufflevector(w10, w11, 0, 1, 2, 3, 4, 5, 6, 7);
      oA[dt] = __builtin_amdgcn_mfma_f32_16x16x32_bf16(frA0, vb0, oA[dt], 0, 0, 0);
      oA[dt] = __builtin_amdgcn_mfma_f32_16x16x32_bf16(frA1, vb1, oA[dt], 0, 0, 0);
      oB[dt] = __builtin_amdgcn_mfma_f32_16x16x32_bf16(frB0, vb0, oB[dt], 0, 0, 0);
      oB[dt] = __builtin_amdgcn_mfma_f32_16x16x32_bf16(frB1, vb1, oB[dt], 0, 0, 0);
    }
    __builtin_amdgcn_s_setprio(0);

    __syncthreads();

    if (kt < 63) {
#pragma unroll
      for (int it = 0; it < 3; ++it) {
        if (it < nbatch) gload16(vp0 + (long)(kt + 1) * 64 + (long)it * 131072,
                                 Vsh + soff0 + 2048 * it);
      }
    }
  }

  {
    float ssum = lrA;
    ssum += __shfl_xor(ssum, 16);
    ssum += __shfl_xor(ssum, 32);
    const float linv = 1.f / ssum;
    float li[4];
#pragma unroll
    for (int r = 0; r < 4; ++r) li[r] = __shfl(linv, sb + lg * 4 + r);
    bf16* ob = out + (long)(b * 4096 + r0 + lg * 4) * 640 + h * 80 + lo;
#pragma unroll
    for (int r = 0; r < 4; ++r)
#pragma unroll
      for (int dt = 0; dt < 5; ++dt)
        ob[(long)r * 640 + dt * 16] = __float2bfloat16(oA[dt][r] * li[r]);
  }
  {
    float ssum = lrB;
    ssum += __shfl_xor(ssum, 16);
    ssum += __shfl_xor(ssum, 32);
    const float linv = 1.f / ssum;
    float li[4];
#pragma unroll
    for (int r = 0; r < 4; ++r) li[r] = __shfl(linv, sb + lg * 4 + r);
    bf16* ob = out + (long)(b * 4096 + r0 + 16 + lg * 4) * 640 + h * 80 + lo;
#pragma unroll
    for (int r = 0; r < 4; ++r)
#pragma unroll
      for (int dt = 0; dt < 5; ++dt)
        ob[(long)r * 640 + dt * 16] = __float2bfloat16(oB[dt][r] * li[r]);
  }
}

// ---------------- Cross-attention v2 (MFMA): 77 keys padded to 80, P in registers ----------------
__global__ __launch_bounds__(256) void cross_kernel(const bf16* __restrict__ q2,
                                                    const bf16* __restrict__ kv2,
                                                    bf16* __restrict__ out) {
  __shared__ bf16 Ksh2[80 * 88];
  __shared__ bf16 Vsh2[80 * 88];
  const int bh = blockIdx.y, b = bh >> 3, h = bh & 7;
  const int tid = threadIdx.x, w = tid >> 6, l = tid & 63;
  const int r0 = blockIdx.x * 128 + w * 32;
  const int lg = l >> 4, lo = l & 15;
  const int sb = l & 48;
  const s16x8 sz = {0, 0, 0, 0, 0, 0, 0, 0};
  const f32x4 fz = {0.f, 0.f, 0.f, 0.f};

  s16x8 qa[2][3];
#pragma unroll
  for (int gq = 0; gq < 2; ++gq) {
    const bf16* qp = q2 + (long)(b * 4096 + r0 + gq * 16 + lo) * 640 + h * 80;
    qa[gq][0] = *(const s16x8*)(qp + lg * 8);
    qa[gq][1] = *(const s16x8*)(qp + 32 + lg * 8);
    qa[gq][2] = (lg < 2) ? *(const s16x8*)(qp + 64 + lg * 8) : sz;
#pragma unroll
    for (int f = 0; f < 3; ++f) {
      s16x8 q = qa[gq][f], r;
#pragma unroll
      for (int i = 0; i < 8; ++i)
        r[i] = (short)(__bfloat16_as_ushort(__float2bfloat16(b2f(q[i]) * QSCALE)));
      qa[gq][f] = r;
    }
  }

  for (int c = tid; c < 800; c += 256) {
    int row = c / 10, s = c % 10;
    s16x8 v = sz;
    if (row < 77)
      v = *(const s16x8*)(kv2 + (long)(b * 77 + row) * 1280 + h * 80 + s * 8);
    *(s16x8*)(Ksh2 + row * 88 + s * 8) = v;
  }
  for (int c = tid; c < 770; c += 256) {
    int j = c / 10, d8 = (c % 10) * 8;
    s16x8 v = *(const s16x8*)(kv2 + (long)(b * 77 + j) * 1280 + 640 + h * 80 + d8);
    const short* vs = (const short*)&v;
#pragma unroll
    for (int i = 0; i < 8; ++i) ((short*)Vsh2)[(d8 + i) * 88 + j] = vs[i];
  }
  if (tid < 240) {
    int d = tid / 3, j = 77 + tid % 3;
    ((short*)Vsh2)[d * 88 + j] = 0;
  }
  __syncthreads();

  float lrA = 0.f, lrB = 0.f;
  f32x4 oA[5], oB[5];
#pragma unroll
  for (int dt = 0; dt < 5; ++dt) { oA[dt] = fz; oB[dt] = fz; }

  unsigned paA[10], paB[10];
  f32x4 s0A, s0B, s1A, s1B;
  {
    s16x8 kb0 = *(const s16x8*)(Ksh2 + lo * 88 + lg * 8);
    s16x8 kb1 = *(const s16x8*)(Ksh2 + lo * 88 + 32 + lg * 8);
    s16x8 kb2 = (lg < 2) ? *(const s16x8*)(Ksh2 + lo * 88 + 64 + lg * 8) : sz;
    __builtin_amdgcn_s_setprio(1);
    s0A = __builtin_amdgcn_mfma_f32_16x16x32_bf16(kb0, qa[0][0], fz, 0, 0, 0);
    s0A = __builtin_amdgcn_mfma_f32_16x16x32_bf16(kb1, qa[0][1], s0A, 0, 0, 0);
    s0A = __builtin_amdgcn_mfma_f32_16x16x32_bf16(kb2, qa[0][2], s0A, 0, 0, 0);
    s0B = __builtin_amdgcn_mfma_f32_16x16x32_bf16(kb0, qa[1][0], fz, 0, 0, 0);
    s0B = __builtin_amdgcn_mfma_f32_16x16x32_bf16(kb1, qa[1][1], s0B, 0, 0, 0);
    s0B = __builtin_amdgcn_mfma_f32_16x16x32_bf16(kb2, qa[1][2], s0B, 0, 0, 0);
    __builtin_amdgcn_s_setprio(0);
  }
#pragma unroll
  for (int ntl = 1; ntl <= 5; ++ntl) {
    if (ntl < 5) {
      s16x8 kb0 = *(const s16x8*)(Ksh2 + (ntl * 16 + lo) * 88 + lg * 8);
      s16x8 kb1 = *(const s16x8*)(Ksh2 + (ntl * 16 + lo) * 88 + 32 + lg * 8);
      s16x8 kb2 = (lg < 2) ? *(const s16x8*)(Ksh2 + (ntl * 16 + lo) * 88 + 64 + lg * 8) : sz;
      __builtin_amdgcn_s_setprio(1);
      s1A = __builtin_amdgcn_mfma_f32_16x16x32_bf16(kb0, qa[0][0], fz, 0, 0, 0);
      s1A = __builtin_amdgcn_mfma_f32_16x16x32_bf16(kb1, qa[0][1], s1A, 0, 0, 0);
      s1A = __builtin_amdgcn_mfma_f32_16x16x32_bf16(kb2, qa[0][2], s1A, 0, 0, 0);
      s1B = __builtin_amdgcn_mfma_f32_16x16x32_bf16(kb0, qa[1][0], fz, 0, 0, 0);
      s1B = __builtin_amdgcn_mfma_f32_16x16x32_bf16(kb1, qa[1][1], s1B, 0, 0, 0);
      s1B = __builtin_amdgcn_mfma_f32_16x16x32_bf16(kb2, qa[1][2], s1B, 0, 0, 0);
      __builtin_amdgcn_s_setprio(0);
    }
    {
      const int pidx = ntl - 1;
      float a0 = __builtin_amdgcn_exp2f(s0A[0]);
      float a1 = __builtin_amdgcn_exp2f(s0A[1]);
      float a2 = __builtin_amdgcn_exp2f(s0A[2]);
      float a3 = __builtin_amdgcn_exp2f(s0A[3]);
      float b0 = __builtin_amdgcn_exp2f(s0B[0]);
      float b1 = __builtin_amdgcn_exp2f(s0B[1]);
      float b2 = __builtin_amdgcn_exp2f(s0B[2]);
      float b3 = __builtin_amdgcn_exp2f(s0B[3]);
      if (pidx == 4) {
        if (lg * 4 + 1 >= 13) { a1 = 0.f; b1 = 0.f; }
        if (lg * 4 + 2 >= 13) { a2 = 0.f; b2 = 0.f; }
        if (lg * 4 + 3 >= 13) { a3 = 0.f; b3 = 0.f; }
      }
      lrA += (a0 + a1) + (a2 + a3);
      lrB += (b0 + b1) + (b2 + b3);
      unsigned u0, u1;
      asm("v_cvt_pk_bf16_f32 %0, %1, %2" : "=v"(u0) : "v"(a0), "v"(a1));
      asm("v_cvt_pk_bf16_f32 %0, %1, %2" : "=v"(u1) : "v"(a2), "v"(a3));
      paA[pidx * 2] = u0;
      paA[pidx * 2 + 1] = u1;
      asm("v_cvt_pk_bf16_f32 %0, %1, %2" : "=v"(u0) : "v"(b0), "v"(b1));
      asm("v_cvt_pk_bf16_f32 %0, %1, %2" : "=v"(u1) : "v"(b2), "v"(b3));
      paB[pidx * 2] = u0;
      paB[pidx * 2 + 1] = u1;
    }
    s0A = s1A;
    s0B = s1B;
  }

  typedef unsigned u32x2 __attribute__((ext_vector_type(2)));
  s16x8 frA0, frA1, frA2, frB0, frB1, frB2;
  {
    u32x2* p;
    p = (u32x2*)&frA0; p[0] = (u32x2){paA[0], paA[1]}; p[1] = (u32x2){paA[2], paA[3]};
    p = (u32x2*)&frA1; p[0] = (u32x2){paA[4], paA[5]}; p[1] = (u32x2){paA[6], paA[7]};
    p = (u32x2*)&frA2; p[0] = (u32x2){paA[8], paA[9]}; p[1] = (u32x2){0u, 0u};
    p = (u32x2*)&frB0; p[0] = (u32x2){paB[0], paB[1]}; p[1] = (u32x2){paB[2], paB[3]};
    p = (u32x2*)&frB1; p[0] = (u32x2){paB[4], paB[5]}; p[1] = (u32x2){paB[6], paB[7]};
    p = (u32x2*)&frB2; p[0] = (u32x2){paB[8], paB[9]}; p[1] = (u32x2){0u, 0u};
  }

  __builtin_amdgcn_s_setprio(1);
#pragma unroll
  for (int dt = 0; dt < 5; ++dt) {
    const bf16* vrow = Vsh2 + (dt * 16 + lo) * 88;
    s16x4 w00 = *(const s16x4*)(vrow + 4 * lg);
    s16x4 w01 = *(const s16x4*)(vrow + 16 + 4 * lg);
    s16x4 w10 = *(const s16x4*)(vrow + 32 + 4 * lg);
    s16x4 w11 = *(const s16x4*)(vrow + 48 + 4 * lg);
    s16x4 w20 = *(const s16x4*)(vrow + 64 + 4 * lg);
    s16x8 vb0 = __builtin_shufflevector(w00, w01, 0, 1, 2, 3, 4, 5, 6, 7);
    s16x8 vb1 = __builtin_shufflevector(w10, w11, 0, 1, 2, 3, 4, 5, 6, 7);
    s16x8 vb2 = __builtin_shufflevector(w20, w20, 0, 1, 2, 3, 0, 1, 2, 3);
    oA[dt] = __builtin_amdgcn_mfma_f32_16x16x32_bf16(frA0, vb0, oA[dt], 0, 0, 0);
    oA[dt] = __builtin_amdgcn_mfma_f32_16x16x32_bf16(frA1, vb1, oA[dt], 0, 0, 0);
    oA[dt] = __builtin_amdgcn_mfma_f32_16x16x32_bf16(frA2, vb2, oA[dt], 0, 0, 0);
    oB[dt] = __builtin_amdgcn_mfma_f32_16x16x32_bf16(frB0, vb0, oB[dt], 0, 0, 0);
    oB[dt] = __builtin_amdgcn_mfma_f32_16x16x32_bf16(frB1, vb1, oB[dt], 0, 0, 0);
    oB[dt] = __builtin_amdgcn_mfma_f32_16x16x32_bf16(frB2, vb2, oB[dt], 0, 0, 0);
  }
  __builtin_amdgcn_s_setprio(0);

  {
    float ssum = lrA;
    ssum += __shfl_xor(ssum, 16);
    ssum += __shfl_xor(ssum, 32);
    const float linv = 1.f / ssum;
    float li[4];
#pragma unroll
    for (int r = 0; r < 4; ++r) li[r] = __shfl(linv, sb + lg * 4 + r);
    bf16* ob = out + (long)(b * 4096 + r0 + lg * 4) * 640 + h * 80 + lo;
#pragma unroll
    for (int r = 0; r < 4; ++r)
#pragma unroll
      for (int dt = 0; dt < 5; ++dt)
        ob[(long)r * 640 + dt * 16] = __float2bfloat16(oA[dt][r] * li[r]);
  }
  {
    float ssum = lrB;
    ssum += __shfl_xor(ssum, 16);
    ssum += __shfl_xor(ssum, 32);
    const float linv = 1.f / ssum;
    float li[4];
#pragma unroll
    for (int r = 0; r < 4; ++r) li[r] = __shfl(linv, sb + lg * 4 + r);
    bf16* ob = out + (long)(b * 4096 + r0 + 16 + lg * 4) * 640 + h * 80 + lo;
#pragma unroll
    for (int r = 0; r < 4; ++r)
#pragma unroll
      for (int dt = 0; dt < 5; ++dt)
        ob[(long)r * 640 + dt * 16] = __float2bfloat16(oB[dt][r] * li[r]);
  }
}

// ---------------- FF1 + GEGLU fused (128x64 tile, BK=64, swizzled LDS) ----------------
__global__ __launch_bounds__(256) void geglu_kernel(const bf16* __restrict__ A,
                                                    const bf16* __restrict__ Bt,
                                                    const float* __restrict__ bias,
                                                    bf16* __restrict__ Cout) {
  __shared__ bf16 Ash[128 * 64];
  __shared__ bf16 Bsh[2][64 * 64];
  const int tid = threadIdx.x, w = tid >> 6, l = tid & 63;
  const int m0 = blockIdx.x * 128, n0 = blockIdx.y * 64;
  const int lo = l & 15, lg = l >> 4, lo7 = l & 7;
  const int mb = w * 32;
  const f32x4 fz = {0.f, 0.f, 0.f, 0.f};
  f32x4 accA[2][4], accG[2][4];
#pragma unroll
  for (int i = 0; i < 2; ++i)
#pragma unroll
    for (int j = 0; j < 4; ++j) { accA[i][j] = fz; accG[i][j] = fz; }

  const int g = tid;
  const int gr = g >> 3;
  const int gcsw = 8 * ((g & 7) ^ (gr & 7));
  const bf16* pa[4];
  const bf16* pb[2][2];
  bf16* la[4];
  bf16* lb[2][2];
#pragma unroll
  for (int s = 0; s < 4; ++s) {
    pa[s] = A + (long)(m0 + gr + 32 * s) * 640 + gcsw;
    la[s] = Ash + (g + 256 * s) * 8;
  }
#pragma unroll
  for (int q = 0; q < 2; ++q)
#pragma unroll
    for (int s = 0; s < 2; ++s) {
      pb[q][s] = Bt + (long)(n0 + q * 2560 + gr + 32 * s) * 640 + gcsw;
      lb[q][s] = Bsh[q] + (g + 256 * s) * 8;
    }

  for (int k0 = 0; k0 < 640; k0 += 64) {
    __syncthreads();
#pragma unroll
    for (int s = 0; s < 4; ++s) { gload16(pa[s], la[s]); pa[s] += 64; }
#pragma unroll
    for (int q = 0; q < 2; ++q)
#pragma unroll
      for (int s = 0; s < 2; ++s) { gload16(pb[q][s], lb[q][s]); pb[q][s] += 64; }
    __syncthreads();
#pragma unroll
    for (int kk = 0; kk < 2; ++kk) {
      const int sl = ((kk * 4 + lg) ^ lo7) * 8;
      s16x8 a[2], ba[4], bg[4];
#pragma unroll
      for (int i = 0; i < 2; ++i)
        a[i] = *(const s16x8*)(Ash + (mb + i * 16 + lo) * 64 + sl);
#pragma unroll
      for (int j = 0; j < 4; ++j) {
        ba[j] = *(const s16x8*)(Bsh[0] + (j * 16 + lo) * 64 + sl);
        bg[j] = *(const s16x8*)(Bsh[1] + (j * 16 + lo) * 64 + sl);
      }
#pragma unroll
      for (int i = 0; i < 2; ++i)
#pragma unroll
        for (int j = 0; j < 4; ++j) {
          accA[i][j] = __builtin_amdgcn_mfma_f32_16x16x32_bf16(a[i], ba[j], accA[i][j], 0, 0, 0);
          accG[i][j] = __builtin_amdgcn_mfma_f32_16x16x32_bf16(a[i], bg[j], accG[i][j], 0, 0, 0);
        }
    }
  }
#pragma unroll
  for (int i = 0; i < 2; ++i) {
#pragma unroll
    for (int j = 0; j < 4; ++j) {
      const int col = n0 + j * 16 + lo;
      const float bA = bias[col];
      const float bG = bias[2560 + col];
#pragma unroll
      for (int r = 0; r < 4; ++r) {
        const long row = m0 + mb + i * 16 + lg * 4 + r;
        const float av = accA[i][j][r] + bA;
        const float gv = accG[i][j][r] + bG;
        const float ge = 0.5f * gv * (1.f + erff(gv * 0.70710678118654752f));
        Cout[row * 2560 + col] = __float2bfloat16(av * ge);
      }
    }
  }
}

// ---------------- host launch ----------------
extern "C" void kernel_launch(void* const* d_in, const int* in_sizes, int n_in,
                              void* d_out, int out_size, void* d_ws, size_t ws_size,
                              hipStream_t stream) {
  (void)in_sizes; (void)n_in; (void)out_size; (void)ws_size;
  const float* x    = (const float*)d_in[0];
  const float* ctx  = (const float*)d_in[1];
  const float* ln1w = (const float*)d_in[2];
  const float* ln1b = (const float*)d_in[3];
  const float* ln2w = (const float*)d_in[4];
  const float* ln2b = (const float*)d_in[5];
  const float* ln3w = (const float*)d_in[6];
  const float* ln3b = (const float*)d_in[7];
  const float* wq1  = (const float*)d_in[8];
  const float* wk1  = (const float*)d_in[9];
  const float* wv1  = (const float*)d_in[10];
  const float* wo1  = (const float*)d_in[11];
  const float* bo1  = (const float*)d_in[12];
  const float* wq2  = (const float*)d_in[13];
  const float* wk2  = (const float*)d_in[14];
  const float* wv2  = (const float*)d_in[15];
  const float* wo2  = (const float*)d_in[16];
  const float* bo2  = (const float*)d_in[17];
  const float* wff1 = (const float*)d_in[18];
  const float* bff1 = (const float*)d_in[19];
  const float* wff2 = (const float*)d_in[20];
  const float* bff2 = (const float*)d_in[21];

  char* ws = (char*)d_ws;
  bf16* Wqkv1 = (bf16*)(ws + 0);           // [1920][640]
  bf16* Wo1t  = (bf16*)(ws + 2457600);     // [640][640]
  bf16* Wq2t  = (bf16*)(ws + 3276800);     // [640][640]
  bf16* Wkv2t = (bf16*)(ws + 4096000);     // [1280][768]
  bf16* Wo2t  = (bf16*)(ws + 6062080);     // [640][640]
  bf16* Wff1t = (bf16*)(ws + 6881280);     // [5120][640]
  bf16* Wff2t = (bf16*)(ws + 13434880);    // [640][2560]
  bf16* Ctxb  = (bf16*)(ws + 16711680);    // [154][768]
  bf16* Hln   = (bf16*)(ws + 16948224);    // [8192][640]
  bf16* X2b   = (bf16*)(ws + 27433984);    // [8192][640] bf16 residual
  bf16* X3b   = (bf16*)(ws + 48405504);    // [8192][640] bf16 residual
  bf16* Qkv   = (bf16*)(ws + 69377024);    // [8192][1920]
  bf16* Ffin  = Qkv;                       // reuse: [8192][2560]
  bf16* Vt    = (bf16*)(ws + 100834304);   // [16][80][4096]
  bf16* Ao    = (bf16*)(ws + 111320064);   // [8192][640]
  bf16* Q2    = (bf16*)(ws + 121805824);   // [8192][640]
  bf16* Kv2   = (bf16*)(ws + 132291584);   // [154][1280]
  float* Outf = (float*)d_out;

  dim3 blk(256);

  // fused weight prep: one launch for all transposes + ctx cvt
  PrepArgs pa;
  const float* srcs[10] = {wq1, wk1, wv1, wo1, wq2, wk2, wv2, wo2, wff1, wff2};
  bf16* dsts[10] = {Wqkv1, Wqkv1 + 640 * 640, Wqkv1 + 2 * 640 * 640, Wo1t, Wq2t,
                    Wkv2t, Wkv2t + 640 * 768, Wo2t, Wff1t, Wff2t};
  int Rs[10] = {640, 640, 640, 640, 640, 768, 768, 640, 640, 2560};
  int Cs[10] = {640, 640, 640, 640, 640, 640, 640, 640, 5120, 640};
  int baseacc = 0;
  for (int j = 0; j < 10; ++j) {
    pa.src[j] = srcs[j];
    pa.dst[j] = dsts[j];
    pa.R[j] = Rs[j];
    pa.C[j] = Cs[j];
    pa.cb[j] = Cs[j] / 32;
    pa.base[j] = baseacc;
    baseacc += (Cs[j] / 32) * (Rs[j] / 32);
  }
  pa.cvtbase = baseacc;            // 8160
  pa.ctx = ctx;
  pa.ctxb = Ctxb;
  const int prep_blocks = baseacc + 116;
  prep_kernel<<<prep_blocks, blk, 0, stream>>>(pa);

  // self-attention block (QKV GEMM writes V transposed directly into Vt)
  ln_kernel<float><<<2048, blk, 0, stream>>>(x, ln1w, ln1b, Hln);
  gemm_kernel<3><<<dim3(64, 15), blk, 0, stream>>>(Hln, Wqkv1, nullptr, (const float*)Vt, Qkv, 8192, 640, 1920);
  flash_kernel<<<dim3(32, 16), blk, 0, stream>>>(Qkv, Vt, Ao);
  gemm64_kernel<4><<<dim3(128, 5), blk, 0, stream>>>(Ao, Wo1t, bo1, x, X2b, 640, 640);
  // cross-attention block
  ln_kernel<bf16><<<2048, blk, 0, stream>>>(X2b, ln2w, ln2b, Hln);
  gemm64_kernel<0><<<dim3(128, 5), blk, 0, stream>>>(Hln, Wq2t, nullptr, nullptr, Q2, 640, 640);
  gemm_kernel<0><<<dim3(2, 10), blk, 0, stream>>>(Ctxb, Wkv2t, nullptr, nullptr, Kv2, 154, 768, 1280);
  cross_kernel<<<dim3(32, 16), blk, 0, stream>>>(Q2, Kv2, Ao);
  gemm64_kernel<5><<<dim3(128, 5), blk, 0, stream>>>(Ao, Wo2t, bo2, X2b, X3b, 640, 640);
  // GEGLU FF block
  ln_kernel<bf16><<<2048, blk, 0, stream>>>(X3b, ln3w, ln3b, Hln);
  geglu_kernel<<<dim3(64, 40), blk, 0, stream>>>(Hln, Wff1t, bff1, Ffin);
  gemm64_kernel<6><<<dim3(128, 5), blk, 0, stream>>>(Ffin, Wff2t, bff2, X3b, Outf, 2560, 640);
}

// Round 18
// 343.677 us; speedup vs baseline: 1.1491x; 1.0037x over previous
//
#include <hip/hip_runtime.h>
#include <hip/hip_bf16.h>

typedef __hip_bfloat16 bf16;
typedef short s16x8 __attribute__((ext_vector_type(8)));
typedef short s16x4 __attribute__((ext_vector_type(4)));
typedef float f32x4 __attribute__((ext_vector_type(4)));

#define SCALE_DH 0.11180339887498949f   // 80^-0.5
#define QSCALE   0.16129820878f         // 80^-0.5 * log2(e)

static __device__ __forceinline__ float b2f(short u) {
  union { float f; unsigned int i; } x;
  x.i = ((unsigned int)(unsigned short)u) << 16;
  return x.f;
}

static __device__ __forceinline__ float tof(float x) { return x; }
static __device__ __forceinline__ float tof(bf16 x) { return __bfloat162float(x); }

static __device__ __forceinline__ void gload16(const bf16* g, bf16* l) {
  __builtin_amdgcn_global_load_lds((__attribute__((address_space(1))) const void*)g,
                                   (__attribute__((address_space(3))) void*)l, 16, 0, 0);
}

// ---------------- fused weight prep: 10 transposes + 1 cvt in one launch ----------------
struct PrepArgs {
  const float* src[10];
  bf16* dst[10];
  int R[10], C[10], cb[10], base[10];
  int cvtbase;
  const float* ctx;
  bf16* ctxb;
};

__global__ __launch_bounds__(256) void prep_kernel(PrepArgs a) {
  const int bid = blockIdx.x;
  if (bid >= a.cvtbase) {
    const int n = 154 * 768;
    int i = ((bid - a.cvtbase) * 256 + threadIdx.x) * 4;
    if (i + 4 <= n) {
      float4 v = *(const float4*)(a.ctx + i);
      a.ctxb[i + 0] = __float2bfloat16(v.x);
      a.ctxb[i + 1] = __float2bfloat16(v.y);
      a.ctxb[i + 2] = __float2bfloat16(v.z);
      a.ctxb[i + 3] = __float2bfloat16(v.w);
    } else {
      for (int k = i; k < n; ++k) a.ctxb[k] = __float2bfloat16(a.ctx[k]);
    }
    return;
  }
  int jid = 0;
#pragma unroll
  for (int k = 1; k < 10; ++k)
    if (bid >= a.base[k]) jid = k;
  const float* in = a.src[jid];
  bf16* out = a.dst[jid];
  const int R = a.R[jid], C = a.C[jid];
  const int lb = bid - a.base[jid];
  const int cblk = lb % a.cb[jid], rblk = lb / a.cb[jid];
  __shared__ float t[32][33];
  const int tx = threadIdx.x & 31, ty = threadIdx.x >> 5;
  const long r0 = (long)rblk * 32, c0 = (long)cblk * 32;
#pragma unroll
  for (int i = 0; i < 4; ++i)
    t[ty + 8 * i][tx] = in[(r0 + ty + 8 * i) * C + c0 + tx];
  __syncthreads();
#pragma unroll
  for (int i = 0; i < 4; ++i)
    out[(c0 + ty + 8 * i) * R + r0 + tx] = __float2bfloat16(t[tx][ty + 8 * i]);
}

// ---------------- LayerNorm D=640: T in -> bf16 out (one wave per row) ----------------
template <typename T>
__global__ __launch_bounds__(256) void ln_kernel(const T* __restrict__ x,
                                                 const float* __restrict__ w,
                                                 const float* __restrict__ b,
                                                 bf16* __restrict__ out) {
  const int wv = threadIdx.x >> 6, l = threadIdx.x & 63;
  const long row = (long)blockIdx.x * 4 + wv;
  const T* xr = x + row * 640;
  float v[10];
  float s = 0.f;
#pragma unroll
  for (int j = 0; j < 10; ++j) { v[j] = tof(xr[l + 64 * j]); s += v[j]; }
#pragma unroll
  for (int o = 32; o > 0; o >>= 1) s += __shfl_xor(s, o);
  const float mean = s * (1.f / 640.f);
  float vs = 0.f;
#pragma unroll
  for (int j = 0; j < 10; ++j) { float d = v[j] - mean; vs += d * d; }
#pragma unroll
  for (int o = 32; o > 0; o >>= 1) vs += __shfl_xor(vs, o);
  const float rstd = rsqrtf(vs * (1.f / 640.f) + 1e-5f);
  bf16* orow = out + row * 640;
#pragma unroll
  for (int j = 0; j < 10; ++j) {
    int d = l + 64 * j;
    orow[d] = __float2bfloat16((v[j] - mean) * rstd * w[d] + b[d]);
  }
}

// ---------------- GEMM 128x128: C[M,N] = A[M,K](bf16) * W, Bt = W^T [N][K] ----------------
// EPI 0: bf16 out. EPI 3 (QKV): bf16 out for col<1280; V cols written TRANSPOSED to vt (res param).
template <int EPI>
__global__ __launch_bounds__(256) void gemm_kernel(const bf16* __restrict__ A,
                                                   const bf16* __restrict__ Bt,
                                                   const float* __restrict__ bias,
                                                   const float* __restrict__ res,
                                                   void* __restrict__ Cout,
                                                   int M, int K, int ldc) {
  __shared__ bf16 Ash[128 * 64];
  __shared__ bf16 Bsh[128 * 64];
  const int tid = threadIdx.x, w = tid >> 6, l = tid & 63;
  const int m0 = blockIdx.x * 128, n0 = blockIdx.y * 128;
  const int mb = (w >> 1) * 64, nb = (w & 1) * 64;
  const int lo = l & 15, lg = l >> 4, lo7 = l & 7;
  const f32x4 fz = {0.f, 0.f, 0.f, 0.f};
  f32x4 acc[4][4];
#pragma unroll
  for (int i = 0; i < 4; ++i)
#pragma unroll
    for (int j = 0; j < 4; ++j) acc[i][j] = fz;

  const int g = tid;
  const int gr = g >> 3;
  const int gcsw = 8 * ((g & 7) ^ (gr & 7));
  const bf16* pa[4];
  const bf16* pb[4];
  bf16* la[4];
  bf16* lb[4];
#pragma unroll
  for (int s = 0; s < 4; ++s) {
    const int rl = gr + 32 * s;
    int ra = m0 + rl; if (ra >= M) ra = M - 1;
    pa[s] = A + (long)ra * K + gcsw;
    pb[s] = Bt + (long)(n0 + rl) * K + gcsw;
    la[s] = Ash + (g + 256 * s) * 8;
    lb[s] = Bsh + (g + 256 * s) * 8;
  }

  for (int k0 = 0; k0 < K; k0 += 64) {
    __syncthreads();
#pragma unroll
    for (int s = 0; s < 4; ++s) {
      gload16(pa[s], la[s]); pa[s] += 64;
      gload16(pb[s], lb[s]); pb[s] += 64;
    }
    __syncthreads();
#pragma unroll
    for (int kk = 0; kk < 2; ++kk) {
      const int sl = ((kk * 4 + lg) ^ lo7) * 8;
      s16x8 a[4], b[4];
#pragma unroll
      for (int i = 0; i < 4; ++i)
        a[i] = *(const s16x8*)(Ash + (mb + i * 16 + lo) * 64 + sl);
#pragma unroll
      for (int j = 0; j < 4; ++j)
        b[j] = *(const s16x8*)(Bsh + (nb + j * 16 + lo) * 64 + sl);
#pragma unroll
      for (int i = 0; i < 4; ++i)
#pragma unroll
        for (int j = 0; j < 4; ++j)
          acc[i][j] = __builtin_amdgcn_mfma_f32_16x16x32_bf16(a[i], b[j], acc[i][j], 0, 0, 0);
    }
  }
  const int rb = m0 + mb + lg * 4;
  const int cb = n0 + nb + lo;
#pragma unroll
  for (int i = 0; i < 4; ++i) {
#pragma unroll
    for (int j = 0; j < 4; ++j) {
      const int col = cb + j * 16;
      if (EPI == 3 && col >= 1280) {
        const int t = col - 1280;
        const int hh = t / 80, dh = t % 80;
        const int row0 = rb + i * 16;
        const int bb = row0 >> 12, n = row0 & 4095;
        s16x4 pk;
#pragma unroll
        for (int r = 0; r < 4; ++r)
          pk[r] = (short)__bfloat16_as_ushort(__float2bfloat16(acc[i][j][r]));
        bf16* vt = (bf16*)res;
        *(s16x4*)(vt + (long)(bb * 8 + hh) * 327680 + (long)dh * 4096 + n) = pk;
        continue;
      }
#pragma unroll
      for (int r = 0; r < 4; ++r) {
        const int row = rb + i * 16 + r;
        if (row < M)
          ((bf16*)Cout)[(long)row * ldc + col] = __float2bfloat16(acc[i][j][r]);
      }
    }
  }
}

// ---------------- GEMM 64x128 (N=640 GEMMs; M % 64 == 0) ----------------
// EPI 0: bf16 out, no bias. EPI 4: bf16 out = acc+bias+f32 res. EPI 5: bf16 out = acc+bias+bf16 res.
// EPI 6: f32 out = acc+bias+bf16 res.
template <int EPI>
__global__ __launch_bounds__(256) void gemm64_kernel(const bf16* __restrict__ A,
                                                     const bf16* __restrict__ Bt,
                                                     const float* __restrict__ bias,
                                                     const void* __restrict__ res,
                                                     void* __restrict__ Cout,
                                                     int K, int ldc) {
  __shared__ bf16 Ash[64 * 64];
  __shared__ bf16 Bsh[128 * 64];
  const int tid = threadIdx.x, w = tid >> 6, l = tid & 63;
  const int m0 = blockIdx.x * 64, n0 = blockIdx.y * 128;
  const int mb = (w & 1) * 32, nb = (w >> 1) * 64;
  const int lo = l & 15, lg = l >> 4, lo7 = l & 7;
  const f32x4 fz = {0.f, 0.f, 0.f, 0.f};
  f32x4 acc[2][4];
#pragma unroll
  for (int i = 0; i < 2; ++i)
#pragma unroll
    for (int j = 0; j < 4; ++j) acc[i][j] = fz;

  const int g = tid;
  const int gr = g >> 3;
  const int gcsw = 8 * ((g & 7) ^ (gr & 7));
  const bf16* pa[2];
  const bf16* pb[4];
  bf16* la[2];
  bf16* lb[4];
#pragma unroll
  for (int s = 0; s < 2; ++s) {
    pa[s] = A + (long)(m0 + gr + 32 * s) * K + gcsw;
    la[s] = Ash + (g + 256 * s) * 8;
  }
#pragma unroll
  for (int s = 0; s < 4; ++s) {
    pb[s] = Bt + (long)(n0 + gr + 32 * s) * K + gcsw;
    lb[s] = Bsh + (g + 256 * s) * 8;
  }

  for (int k0 = 0; k0 < K; k0 += 64) {
    __syncthreads();
#pragma unroll
    for (int s = 0; s < 2; ++s) { gload16(pa[s], la[s]); pa[s] += 64; }
#pragma unroll
    for (int s = 0; s < 4; ++s) { gload16(pb[s], lb[s]); pb[s] += 64; }
    __syncthreads();
#pragma unroll
    for (int kk = 0; kk < 2; ++kk) {
      const int sl = ((kk * 4 + lg) ^ lo7) * 8;
      s16x8 a[2], b[4];
#pragma unroll
      for (int i = 0; i < 2; ++i)
        a[i] = *(const s16x8*)(Ash + (mb + i * 16 + lo) * 64 + sl);
#pragma unroll
      for (int j = 0; j < 4; ++j)
        b[j] = *(const s16x8*)(Bsh + (nb + j * 16 + lo) * 64 + sl);
#pragma unroll
      for (int i = 0; i < 2; ++i)
#pragma unroll
        for (int j = 0; j < 4; ++j)
          acc[i][j] = __builtin_amdgcn_mfma_f32_16x16x32_bf16(a[i], b[j], acc[i][j], 0, 0, 0);
    }
  }
  const int rb = m0 + mb + lg * 4;
  const int cb = n0 + nb + lo;
#pragma unroll
  for (int i = 0; i < 2; ++i) {
#pragma unroll
    for (int j = 0; j < 4; ++j) {
      const int col = cb + j * 16;
      float bv = 0.f;
      if (EPI >= 4) bv = bias[col];
#pragma unroll
      for (int r = 0; r < 4; ++r) {
        const int row = rb + i * 16 + r;
        const long idx = (long)row * ldc + col;
        float v = acc[i][j][r] + bv;
        if (EPI == 4) {
          v += ((const float*)res)[idx];
          ((bf16*)Cout)[idx] = __float2bfloat16(v);
        } else if (EPI == 5) {
          v += __bfloat162float(((const bf16*)res)[idx]);
          ((bf16*)Cout)[idx] = __float2bfloat16(v);
        } else if (EPI == 6) {
          v += __bfloat162float(((const bf16*)res)[idx]);
          ((float*)Cout)[idx] = v;
        } else {
          ((bf16*)Cout)[idx] = __float2bfloat16(v);
        }
      }
    }
  }
}

// ---------------- Flash self-attention v15: K/V double-buffer, ONE barrier per tile ----------------
// Per tile t: issue K/V(t+1) -> buf[cur^1] | QK+SM from Kbuf[cur] | PV from Vbuf[cur] | barrier.
// The barrier drains the t+1 loads, whose landing window is now the whole tile phase.
__global__ __launch_bounds__(256, 3) void flash_kernel(const bf16* __restrict__ qkv,
                                                       const bf16* __restrict__ vT,
                                                       bf16* __restrict__ out) {
  __shared__ bf16 Ksh[2][64 * 80];
  __shared__ bf16 Vsh[2][80 * 64];
  const int bh = blockIdx.y, b = bh >> 3, h = bh & 7;
  const int tid = threadIdx.x, w = tid >> 6, l = tid & 63;
  const int r0 = blockIdx.x * 128 + w * 32;
  const int lg = l >> 4, lo = l & 15, lo7 = l & 7;
  const int sb = l & 48;
  const s16x8 sz = {0, 0, 0, 0, 0, 0, 0, 0};
  const f32x4 fz = {0.f, 0.f, 0.f, 0.f};

  s16x8 qa[2][3];
#pragma unroll
  for (int gq = 0; gq < 2; ++gq) {
    const bf16* qp = qkv + (long)(b * 4096 + r0 + gq * 16 + lo) * 1920 + h * 80;
    qa[gq][0] = *(const s16x8*)(qp + lg * 8);
    qa[gq][1] = *(const s16x8*)(qp + 32 + lg * 8);
    qa[gq][2] = (lg < 2) ? *(const s16x8*)(qp + 64 + lg * 8) : sz;
#pragma unroll
    for (int f = 0; f < 3; ++f) {
      s16x8 q = qa[gq][f], r;
#pragma unroll
      for (int i = 0; i < 8; ++i)
        r[i] = (short)(__bfloat16_as_ushort(__float2bfloat16(b2f(q[i]) * QSCALE)));
      qa[gq][f] = r;
    }
  }

  const bf16* kp[3];
  const int nbatch = (w < 2) ? 3 : 2;
#pragma unroll
  for (int it = 0; it < 3; ++it) {
    int g = tid + 256 * it;
    int gc = (g < 640) ? g : 0;
    int krow = gc / 10, ksl = gc % 10;
    int ksrc = (ksl < 8) ? (ksl ^ (krow & 7)) : (8 + ((ksl - 8) ^ ((krow >> 2) & 1)));
    kp[it] = qkv + (long)(b * 4096 + krow) * 1920 + 640 + h * 80 + ksrc * 8;
  }
  const bf16* vp0 = vT + (long)bh * 327680 + (long)(tid >> 3) * 4096 +
                    (((tid & 7) ^ ((tid >> 3) & 7)) * 8);
  const int soff0 = tid * 8;

  const int voff0 = (((lg >> 1) + 0) ^ lo7) * 8 + 4 * (lg & 1);
  const int voff1 = (((lg >> 1) + 2) ^ lo7) * 8 + 4 * (lg & 1);
  const int voff2 = (((lg >> 1) + 4) ^ lo7) * 8 + 4 * (lg & 1);
  const int voff3 = (((lg >> 1) + 6) ^ lo7) * 8 + 4 * (lg & 1);

  float lrA = 0.f, lrB = 0.f;
  f32x4 oA[5], oB[5];
#pragma unroll
  for (int dt = 0; dt < 5; ++dt) { oA[dt] = fz; oB[dt] = fz; }

  // prologue: stage tile 0 into buffer 0
#pragma unroll
  for (int it = 0; it < 3; ++it) {
    if (it < nbatch) {
      gload16(kp[it], Ksh[0] + soff0 + 2048 * it); kp[it] += 64 * 1920;
      gload16(vp0 + (long)it * 131072, Vsh[0] + soff0 + 2048 * it);
    }
  }
  __syncthreads();

  for (int kt = 0; kt < 64; ++kt) {
    const int cur = kt & 1;
    const bf16* kbuf = Ksh[cur];
    const bf16* vbuf = Vsh[cur];

    // issue K/V(t+1) into the other buffer — lands any time before end-of-tile barrier
    if (kt < 63) {
#pragma unroll
      for (int it = 0; it < 3; ++it) {
        if (it < nbatch) {
          gload16(kp[it], Ksh[cur ^ 1] + soff0 + 2048 * it); kp[it] += 64 * 1920;
          gload16(vp0 + (long)(kt + 1) * 64 + (long)it * 131072, Vsh[cur ^ 1] + soff0 + 2048 * it);
        }
      }
    }

    unsigned paA[8], paB[8];
    f32x4 s0A, s0B, s1A, s1B;
    {
      s16x8 kb0 = *(const s16x8*)(kbuf + lo * 80 + ((lg ^ lo7)) * 8);
      s16x8 kb1 = *(const s16x8*)(kbuf + lo * 80 + (((4 + lg) ^ lo7)) * 8);
      s16x8 kb2 = (lg < 2) ? *(const s16x8*)(kbuf + lo * 80 + 64 + ((lg ^ ((lo >> 2) & 1))) * 8) : sz;
      __builtin_amdgcn_s_setprio(1);
      s0A = __builtin_amdgcn_mfma_f32_16x16x32_bf16(kb0, qa[0][0], fz, 0, 0, 0);
      s0A = __builtin_amdgcn_mfma_f32_16x16x32_bf16(kb1, qa[0][1], s0A, 0, 0, 0);
      s0A = __builtin_amdgcn_mfma_f32_16x16x32_bf16(kb2, qa[0][2], s0A, 0, 0, 0);
      s0B = __builtin_amdgcn_mfma_f32_16x16x32_bf16(kb0, qa[1][0], fz, 0, 0, 0);
      s0B = __builtin_amdgcn_mfma_f32_16x16x32_bf16(kb1, qa[1][1], s0B, 0, 0, 0);
      s0B = __builtin_amdgcn_mfma_f32_16x16x32_bf16(kb2, qa[1][2], s0B, 0, 0, 0);
      __builtin_amdgcn_s_setprio(0);
    }
#pragma unroll
    for (int ntl = 1; ntl <= 4; ++ntl) {
      if (ntl < 4) {
        s16x8 kb0 = *(const s16x8*)(kbuf + (ntl * 16 + lo) * 80 + ((lg ^ lo7)) * 8);
        s16x8 kb1 = *(const s16x8*)(kbuf + (ntl * 16 + lo) * 80 + (((4 + lg) ^ lo7)) * 8);
        s16x8 kb2 = (lg < 2)
                        ? *(const s16x8*)(kbuf + (ntl * 16 + lo) * 80 + 64 + ((lg ^ ((lo >> 2) & 1))) * 8)
                        : sz;
        __builtin_amdgcn_s_setprio(1);
        s1A = __builtin_amdgcn_mfma_f32_16x16x32_bf16(kb0, qa[0][0], fz, 0, 0, 0);
        s1A = __builtin_amdgcn_mfma_f32_16x16x32_bf16(kb1, qa[0][1], s1A, 0, 0, 0);
        s1A = __builtin_amdgcn_mfma_f32_16x16x32_bf16(kb2, qa[0][2], s1A, 0, 0, 0);
        s1B = __builtin_amdgcn_mfma_f32_16x16x32_bf16(kb0, qa[1][0], fz, 0, 0, 0);
        s1B = __builtin_amdgcn_mfma_f32_16x16x32_bf16(kb1, qa[1][1], s1B, 0, 0, 0);
        s1B = __builtin_amdgcn_mfma_f32_16x16x32_bf16(kb2, qa[1][2], s1B, 0, 0, 0);
        __builtin_amdgcn_s_setprio(0);
      }
      {
        const int pidx = ntl - 1;
        float a0 = __builtin_amdgcn_exp2f(s0A[0]);
        float a1 = __builtin_amdgcn_exp2f(s0A[1]);
        float a2 = __builtin_amdgcn_exp2f(s0A[2]);
        float a3 = __builtin_amdgcn_exp2f(s0A[3]);
        lrA += (a0 + a1) + (a2 + a3);
        unsigned u0, u1;
        asm("v_cvt_pk_bf16_f32 %0, %1, %2" : "=v"(u0) : "v"(a0), "v"(a1));
        asm("v_cvt_pk_bf16_f32 %0, %1, %2" : "=v"(u1) : "v"(a2), "v"(a3));
        paA[pidx * 2] = u0;
        paA[pidx * 2 + 1] = u1;
        float b0 = __builtin_amdgcn_exp2f(s0B[0]);
        float b1 = __builtin_amdgcn_exp2f(s0B[1]);
        float b2 = __builtin_amdgcn_exp2f(s0B[2]);
        float b3 = __builtin_amdgcn_exp2f(s0B[3]);
        lrB += (b0 + b1) + (b2 + b3);
        asm("v_cvt_pk_bf16_f32 %0, %1, %2" : "=v"(u0) : "v"(b0), "v"(b1));
        asm("v_cvt_pk_bf16_f32 %0, %1, %2" : "=v"(u1) : "v"(b2), "v"(b3));
        paB[pidx * 2] = u0;
        paB[pidx * 2 + 1] = u1;
      }
      s0A = s1A;
      s0B = s1B;
    }

    typedef unsigned u32x2 __attribute__((ext_vector_type(2)));
    s16x8 frA0, frA1, frB0, frB1;
    {
      u32x2* p;
      p = (u32x2*)&frA0; p[0] = (u32x2){paA[0], paA[1]}; p[1] = (u32x2){paA[2], paA[3]};
      p = (u32x2*)&frA1; p[0] = (u32x2){paA[4], paA[5]}; p[1] = (u32x2){paA[6], paA[7]};
      p = (u32x2*)&frB0; p[0] = (u32x2){paB[0], paB[1]}; p[1] = (u32x2){paB[2], paB[3]};
      p = (u32x2*)&frB1; p[0] = (u32x2){paB[4], paB[5]}; p[1] = (u32x2){paB[6], paB[7]};
    }

    __builtin_amdgcn_s_setprio(1);
#pragma unroll
    for (int dt = 0; dt < 5; ++dt) {
      const bf16* vrow = vbuf + (dt * 16 + lo) * 64;
      s16x4 w00 = *(const s16x4*)(vrow + voff0);
      s16x4 w01 = *(const s16x4*)(vrow + voff1);
      s16x4 w10 = *(const s16x4*)(vrow + voff2);
      s16x4 w11 = *(const s16x4*)(vrow + voff3);
      s16x8 vb0 = __builtin_shufflevector(w00, w01, 0, 1, 2, 3, 4, 5, 6, 7);
      s16x8 vb1 = __builtin_shufflevector(w10, w11, 0, 1, 2, 3, 4, 5, 6, 7);
      oA[dt] = __builtin_amdgcn_mfma_f32_16x16x32_bf16(frA0, vb0, oA[dt], 0, 0, 0);
      oA[dt] = __builtin_amdgcn_mfma_f32_16x16x32_bf16(frA1, vb1, oA[dt], 0, 0, 0);
      oB[dt] = __builtin_amdgcn_mfma_f32_16x16x32_bf16(frB0, vb0, oB[dt], 0, 0, 0);
      oB[dt] = __builtin_amdgcn_mfma_f32_16x16x32_bf16(frB1, vb1, oB[dt], 0, 0, 0);
    }
    __builtin_amdgcn_s_setprio(0);

    __syncthreads();   // waves done reading buf[cur]; drains K/V(t+1) into buf[cur^1]
  }

  {
    float ssum = lrA;
    ssum += __shfl_xor(ssum, 16);
    ssum += __shfl_xor(ssum, 32);
    const float linv = 1.f / ssum;
    float li[4];
#pragma unroll
    for (int r = 0; r < 4; ++r) li[r] = __shfl(linv, sb + lg * 4 + r);
    bf16* ob = out + (long)(b * 4096 + r0 + lg * 4) * 640 + h * 80 + lo;
#pragma unroll
    for (int r = 0; r < 4; ++r)
#pragma unroll
      for (int dt = 0; dt < 5; ++dt)
        ob[(long)r * 640 + dt * 16] = __float2bfloat16(oA[dt][r] * li[r]);
  }
  {
    float ssum = lrB;
    ssum += __shfl_xor(ssum, 16);
    ssum += __shfl_xor(ssum, 32);
    const float linv = 1.f / ssum;
    float li[4];
#pragma unroll
    for (int r = 0; r < 4; ++r) li[r] = __shfl(linv, sb + lg * 4 + r);
    bf16* ob = out + (long)(b * 4096 + r0 + 16 + lg * 4) * 640 + h * 80 + lo;
#pragma unroll
    for (int r = 0; r < 4; ++r)
#pragma unroll
      for (int dt = 0; dt < 5; ++dt)
        ob[(long)r * 640 + dt * 16] = __float2bfloat16(oB[dt][r] * li[r]);
  }
}

// ---------------- Cross-attention v2 (MFMA): 77 keys padded to 80, P in registers ----------------
__global__ __launch_bounds__(256) void cross_kernel(const bf16* __restrict__ q2,
                                                    const bf16* __restrict__ kv2,
                                                    bf16* __restrict__ out) {
  __shared__ bf16 Ksh2[80 * 88];
  __shared__ bf16 Vsh2[80 * 88];
  const int bh = blockIdx.y, b = bh >> 3, h = bh & 7;
  const int tid = threadIdx.x, w = tid >> 6, l = tid & 63;
  const int r0 = blockIdx.x * 128 + w * 32;
  const int lg = l >> 4, lo = l & 15;
  const int sb = l & 48;
  const s16x8 sz = {0, 0, 0, 0, 0, 0, 0, 0};
  const f32x4 fz = {0.f, 0.f, 0.f, 0.f};

  s16x8 qa[2][3];
#pragma unroll
  for (int gq = 0; gq < 2; ++gq) {
    const bf16* qp = q2 + (long)(b * 4096 + r0 + gq * 16 + lo) * 640 + h * 80;
    qa[gq][0] = *(const s16x8*)(qp + lg * 8);
    qa[gq][1] = *(const s16x8*)(qp + 32 + lg * 8);
    qa[gq][2] = (lg < 2) ? *(const s16x8*)(qp + 64 + lg * 8) : sz;
#pragma unroll
    for (int f = 0; f < 3; ++f) {
      s16x8 q = qa[gq][f], r;
#pragma unroll
      for (int i = 0; i < 8; ++i)
        r[i] = (short)(__bfloat16_as_ushort(__float2bfloat16(b2f(q[i]) * QSCALE)));
      qa[gq][f] = r;
    }
  }

  for (int c = tid; c < 800; c += 256) {
    int row = c / 10, s = c % 10;
    s16x8 v = sz;
    if (row < 77)
      v = *(const s16x8*)(kv2 + (long)(b * 77 + row) * 1280 + h * 80 + s * 8);
    *(s16x8*)(Ksh2 + row * 88 + s * 8) = v;
  }
  for (int c = tid; c < 770; c += 256) {
    int j = c / 10, d8 = (c % 10) * 8;
    s16x8 v = *(const s16x8*)(kv2 + (long)(b * 77 + j) * 1280 + 640 + h * 80 + d8);
    const short* vs = (const short*)&v;
#pragma unroll
    for (int i = 0; i < 8; ++i) ((short*)Vsh2)[(d8 + i) * 88 + j] = vs[i];
  }
  if (tid < 240) {
    int d = tid / 3, j = 77 + tid % 3;
    ((short*)Vsh2)[d * 88 + j] = 0;
  }
  __syncthreads();

  float lrA = 0.f, lrB = 0.f;
  f32x4 oA[5], oB[5];
#pragma unroll
  for (int dt = 0; dt < 5; ++dt) { oA[dt] = fz; oB[dt] = fz; }

  unsigned paA[10], paB[10];
  f32x4 s0A, s0B, s1A, s1B;
  {
    s16x8 kb0 = *(const s16x8*)(Ksh2 + lo * 88 + lg * 8);
    s16x8 kb1 = *(const s16x8*)(Ksh2 + lo * 88 + 32 + lg * 8);
    s16x8 kb2 = (lg < 2) ? *(const s16x8*)(Ksh2 + lo * 88 + 64 + lg * 8) : sz;
    __builtin_amdgcn_s_setprio(1);
    s0A = __builtin_amdgcn_mfma_f32_16x16x32_bf16(kb0, qa[0][0], fz, 0, 0, 0);
    s0A = __builtin_amdgcn_mfma_f32_16x16x32_bf16(kb1, qa[0][1], s0A, 0, 0, 0);
    s0A = __builtin_amdgcn_mfma_f32_16x16x32_bf16(kb2, qa[0][2], s0A, 0, 0, 0);
    s0B = __builtin_amdgcn_mfma_f32_16x16x32_bf16(kb0, qa[1][0], fz, 0, 0, 0);
    s0B = __builtin_amdgcn_mfma_f32_16x16x32_bf16(kb1, qa[1][1], s0B, 0, 0, 0);
    s0B = __builtin_amdgcn_mfma_f32_16x16x32_bf16(kb2, qa[1][2], s0B, 0, 0, 0);
    __builtin_amdgcn_s_setprio(0);
  }
#pragma unroll
  for (int ntl = 1; ntl <= 5; ++ntl) {
    if (ntl < 5) {
      s16x8 kb0 = *(const s16x8*)(Ksh2 + (ntl * 16 + lo) * 88 + lg * 8);
      s16x8 kb1 = *(const s16x8*)(Ksh2 + (ntl * 16 + lo) * 88 + 32 + lg * 8);
      s16x8 kb2 = (lg < 2) ? *(const s16x8*)(Ksh2 + (ntl * 16 + lo) * 88 + 64 + lg * 8) : sz;
      __builtin_amdgcn_s_setprio(1);
      s1A = __builtin_amdgcn_mfma_f32_16x16x32_bf16(kb0, qa[0][0], fz, 0, 0, 0);
      s1A = __builtin_amdgcn_mfma_f32_16x16x32_bf16(kb1, qa[0][1], s1A, 0, 0, 0);
      s1A = __builtin_amdgcn_mfma_f32_16x16x32_bf16(kb2, qa[0][2], s1A, 0, 0, 0);
      s1B = __builtin_amdgcn_mfma_f32_16x16x32_bf16(kb0, qa[1][0], fz, 0, 0, 0);
      s1B = __builtin_amdgcn_mfma_f32_16x16x32_bf16(kb1, qa[1][1], s1B, 0, 0, 0);
      s1B = __builtin_amdgcn_mfma_f32_16x16x32_bf16(kb2, qa[1][2], s1B, 0, 0, 0);
      __builtin_amdgcn_s_setprio(0);
    }
    {
      const int pidx = ntl - 1;
      float a0 = __builtin_amdgcn_exp2f(s0A[0]);
      float a1 = __builtin_amdgcn_exp2f(s0A[1]);
      float a2 = __builtin_amdgcn_exp2f(s0A[2]);
      float a3 = __builtin_amdgcn_exp2f(s0A[3]);
      float b0 = __builtin_amdgcn_exp2f(s0B[0]);
      float b1 = __builtin_amdgcn_exp2f(s0B[1]);
      float b2 = __builtin_amdgcn_exp2f(s0B[2]);
      float b3 = __builtin_amdgcn_exp2f(s0B[3]);
      if (pidx == 4) {
        if (lg * 4 + 1 >= 13) { a1 = 0.f; b1 = 0.f; }
        if (lg * 4 + 2 >= 13) { a2 = 0.f; b2 = 0.f; }
        if (lg * 4 + 3 >= 13) { a3 = 0.f; b3 = 0.f; }
      }
      lrA += (a0 + a1) + (a2 + a3);
      lrB += (b0 + b1) + (b2 + b3);
      unsigned u0, u1;
      asm("v_cvt_pk_bf16_f32 %0, %1, %2" : "=v"(u0) : "v"(a0), "v"(a1));
      asm("v_cvt_pk_bf16_f32 %0, %1, %2" : "=v"(u1) : "v"(a2), "v"(a3));
      paA[pidx * 2] = u0;
      paA[pidx * 2 + 1] = u1;
      asm("v_cvt_pk_bf16_f32 %0, %1, %2" : "=v"(u0) : "v"(b0), "v"(b1));
      asm("v_cvt_pk_bf16_f32 %0, %1, %2" : "=v"(u1) : "v"(b2), "v"(b3));
      paB[pidx * 2] = u0;
      paB[pidx * 2 + 1] = u1;
    }
    s0A = s1A;
    s0B = s1B;
  }

  typedef unsigned u32x2 __attribute__((ext_vector_type(2)));
  s16x8 frA0, frA1, frA2, frB0, frB1, frB2;
  {
    u32x2* p;
    p = (u32x2*)&frA0; p[0] = (u32x2){paA[0], paA[1]}; p[1] = (u32x2){paA[2], paA[3]};
    p = (u32x2*)&frA1; p[0] = (u32x2){paA[4], paA[5]}; p[1] = (u32x2){paA[6], paA[7]};
    p = (u32x2*)&frA2; p[0] = (u32x2){paA[8], paA[9]}; p[1] = (u32x2){0u, 0u};
    p = (u32x2*)&frB0; p[0] = (u32x2){paB[0], paB[1]}; p[1] = (u32x2){paB[2], paB[3]};
    p = (u32x2*)&frB1; p[0] = (u32x2){paB[4], paB[5]}; p[1] = (u32x2){paB[6], paB[7]};
    p = (u32x2*)&frB2; p[0] = (u32x2){paB[8], paB[9]}; p[1] = (u32x2){0u, 0u};
  }

  __builtin_amdgcn_s_setprio(1);
#pragma unroll
  for (int dt = 0; dt < 5; ++dt) {
    const bf16* vrow = Vsh2 + (dt * 16 + lo) * 88;
    s16x4 w00 = *(const s16x4*)(vrow + 4 * lg);
    s16x4 w01 = *(const s16x4*)(vrow + 16 + 4 * lg);
    s16x4 w10 = *(const s16x4*)(vrow + 32 + 4 * lg);
    s16x4 w11 = *(const s16x4*)(vrow + 48 + 4 * lg);
    s16x4 w20 = *(const s16x4*)(vrow + 64 + 4 * lg);
    s16x8 vb0 = __builtin_shufflevector(w00, w01, 0, 1, 2, 3, 4, 5, 6, 7);
    s16x8 vb1 = __builtin_shufflevector(w10, w11, 0, 1, 2, 3, 4, 5, 6, 7);
    s16x8 vb2 = __builtin_shufflevector(w20, w20, 0, 1, 2, 3, 0, 1, 2, 3);
    oA[dt] = __builtin_amdgcn_mfma_f32_16x16x32_bf16(frA0, vb0, oA[dt], 0, 0, 0);
    oA[dt] = __builtin_amdgcn_mfma_f32_16x16x32_bf16(frA1, vb1, oA[dt], 0, 0, 0);
    oA[dt] = __builtin_amdgcn_mfma_f32_16x16x32_bf16(frA2, vb2, oA[dt], 0, 0, 0);
    oB[dt] = __builtin_amdgcn_mfma_f32_16x16x32_bf16(frB0, vb0, oB[dt], 0, 0, 0);
    oB[dt] = __builtin_amdgcn_mfma_f32_16x16x32_bf16(frB1, vb1, oB[dt], 0, 0, 0);
    oB[dt] = __builtin_amdgcn_mfma_f32_16x16x32_bf16(frB2, vb2, oB[dt], 0, 0, 0);
  }
  __builtin_amdgcn_s_setprio(0);

  {
    float ssum = lrA;
    ssum += __shfl_xor(ssum, 16);
    ssum += __shfl_xor(ssum, 32);
    const float linv = 1.f / ssum;
    float li[4];
#pragma unroll
    for (int r = 0; r < 4; ++r) li[r] = __shfl(linv, sb + lg * 4 + r);
    bf16* ob = out + (long)(b * 4096 + r0 + lg * 4) * 640 + h * 80 + lo;
#pragma unroll
    for (int r = 0; r < 4; ++r)
#pragma unroll
      for (int dt = 0; dt < 5; ++dt)
        ob[(long)r * 640 + dt * 16] = __float2bfloat16(oA[dt][r] * li[r]);
  }
  {
    float ssum = lrB;
    ssum += __shfl_xor(ssum, 16);
    ssum += __shfl_xor(ssum, 32);
    const float linv = 1.f / ssum;
    float li[4];
#pragma unroll
    for (int r = 0; r < 4; ++r) li[r] = __shfl(linv, sb + lg * 4 + r);
    bf16* ob = out + (long)(b * 4096 + r0 + 16 + lg * 4) * 640 + h * 80 + lo;
#pragma unroll
    for (int r = 0; r < 4; ++r)
#pragma unroll
      for (int dt = 0; dt < 5; ++dt)
        ob[(long)r * 640 + dt * 16] = __float2bfloat16(oB[dt][r] * li[r]);
  }
}

// ---------------- FF1 + GEGLU fused (128x64 tile, BK=64, swizzled LDS) ----------------
__global__ __launch_bounds__(256) void geglu_kernel(const bf16* __restrict__ A,
                                                    const bf16* __restrict__ Bt,
                                                    const float* __restrict__ bias,
                                                    bf16* __restrict__ Cout) {
  __shared__ bf16 Ash[128 * 64];
  __shared__ bf16 Bsh[2][64 * 64];
  const int tid = threadIdx.x, w = tid >> 6, l = tid & 63;
  const int m0 = blockIdx.x * 128, n0 = blockIdx.y * 64;
  const int lo = l & 15, lg = l >> 4, lo7 = l & 7;
  const int mb = w * 32;
  const f32x4 fz = {0.f, 0.f, 0.f, 0.f};
  f32x4 accA[2][4], accG[2][4];
#pragma unroll
  for (int i = 0; i < 2; ++i)
#pragma unroll
    for (int j = 0; j < 4; ++j) { accA[i][j] = fz; accG[i][j] = fz; }

  const int g = tid;
  const int gr = g >> 3;
  const int gcsw = 8 * ((g & 7) ^ (gr & 7));
  const bf16* pa[4];
  const bf16* pb[2][2];
  bf16* la[4];
  bf16* lb[2][2];
#pragma unroll
  for (int s = 0; s < 4; ++s) {
    pa[s] = A + (long)(m0 + gr + 32 * s) * 640 + gcsw;
    la[s] = Ash + (g + 256 * s) * 8;
  }
#pragma unroll
  for (int q = 0; q < 2; ++q)
#pragma unroll
    for (int s = 0; s < 2; ++s) {
      pb[q][s] = Bt + (long)(n0 + q * 2560 + gr + 32 * s) * 640 + gcsw;
      lb[q][s] = Bsh[q] + (g + 256 * s) * 8;
    }

  for (int k0 = 0; k0 < 640; k0 += 64) {
    __syncthreads();
#pragma unroll
    for (int s = 0; s < 4; ++s) { gload16(pa[s], la[s]); pa[s] += 64; }
#pragma unroll
    for (int q = 0; q < 2; ++q)
#pragma unroll
      for (int s = 0; s < 2; ++s) { gload16(pb[q][s], lb[q][s]); pb[q][s] += 64; }
    __syncthreads();
#pragma unroll
    for (int kk = 0; kk < 2; ++kk) {
      const int sl = ((kk * 4 + lg) ^ lo7) * 8;
      s16x8 a[2], ba[4], bg[4];
#pragma unroll
      for (int i = 0; i < 2; ++i)
        a[i] = *(const s16x8*)(Ash + (mb + i * 16 + lo) * 64 + sl);
#pragma unroll
      for (int j = 0; j < 4; ++j) {
        ba[j] = *(const s16x8*)(Bsh[0] + (j * 16 + lo) * 64 + sl);
        bg[j] = *(const s16x8*)(Bsh[1] + (j * 16 + lo) * 64 + sl);
      }
#pragma unroll
      for (int i = 0; i < 2; ++i)
#pragma unroll
        for (int j = 0; j < 4; ++j) {
          accA[i][j] = __builtin_amdgcn_mfma_f32_16x16x32_bf16(a[i], ba[j], accA[i][j], 0, 0, 0);
          accG[i][j] = __builtin_amdgcn_mfma_f32_16x16x32_bf16(a[i], bg[j], accG[i][j], 0, 0, 0);
        }
    }
  }
#pragma unroll
  for (int i = 0; i < 2; ++i) {
#pragma unroll
    for (int j = 0; j < 4; ++j) {
      const int col = n0 + j * 16 + lo;
      const float bA = bias[col];
      const float bG = bias[2560 + col];
#pragma unroll
      for (int r = 0; r < 4; ++r) {
        const long row = m0 + mb + i * 16 + lg * 4 + r;
        const float av = accA[i][j][r] + bA;
        const float gv = accG[i][j][r] + bG;
        const float ge = 0.5f * gv * (1.f + erff(gv * 0.70710678118654752f));
        Cout[row * 2560 + col] = __float2bfloat16(av * ge);
      }
    }
  }
}

// ---------------- host launch ----------------
extern "C" void kernel_launch(void* const* d_in, const int* in_sizes, int n_in,
                              void* d_out, int out_size, void* d_ws, size_t ws_size,
                              hipStream_t stream) {
  (void)in_sizes; (void)n_in; (void)out_size; (void)ws_size;
  const float* x    = (const float*)d_in[0];
  const float* ctx  = (const float*)d_in[1];
  const float* ln1w = (const float*)d_in[2];
  const float* ln1b = (const float*)d_in[3];
  const float* ln2w = (const float*)d_in[4];
  const float* ln2b = (const float*)d_in[5];
  const float* ln3w = (const float*)d_in[6];
  const float* ln3b = (const float*)d_in[7];
  const float* wq1  = (const float*)d_in[8];
  const float* wk1  = (const float*)d_in[9];
  const float* wv1  = (const float*)d_in[10];
  const float* wo1  = (const float*)d_in[11];
  const float* bo1  = (const float*)d_in[12];
  const float* wq2  = (const float*)d_in[13];
  const float* wk2  = (const float*)d_in[14];
  const float* wv2  = (const float*)d_in[15];
  const float* wo2  = (const float*)d_in[16];
  const float* bo2  = (const float*)d_in[17];
  const float* wff1 = (const float*)d_in[18];
  const float* bff1 = (const float*)d_in[19];
  const float* wff2 = (const float*)d_in[20];
  const float* bff2 = (const float*)d_in[21];

  char* ws = (char*)d_ws;
  bf16* Wqkv1 = (bf16*)(ws + 0);           // [1920][640]
  bf16* Wo1t  = (bf16*)(ws + 2457600);     // [640][640]
  bf16* Wq2t  = (bf16*)(ws + 3276800);     // [640][640]
  bf16* Wkv2t = (bf16*)(ws + 4096000);     // [1280][768]
  bf16* Wo2t  = (bf16*)(ws + 6062080);     // [640][640]
  bf16* Wff1t = (bf16*)(ws + 6881280);     // [5120][640]
  bf16* Wff2t = (bf16*)(ws + 13434880);    // [640][2560]
  bf16* Ctxb  = (bf16*)(ws + 16711680);    // [154][768]
  bf16* Hln   = (bf16*)(ws + 16948224);    // [8192][640]
  bf16* X2b   = (bf16*)(ws + 27433984);    // [8192][640] bf16 residual
  bf16* X3b   = (bf16*)(ws + 48405504);    // [8192][640] bf16 residual
  bf16* Qkv   = (bf16*)(ws + 69377024);    // [8192][1920]
  bf16* Ffin  = Qkv;                       // reuse: [8192][2560]
  bf16* Vt    = (bf16*)(ws + 100834304);   // [16][80][4096]
  bf16* Ao    = (bf16*)(ws + 111320064);   // [8192][640]
  bf16* Q2    = (bf16*)(ws + 121805824);   // [8192][640]
  bf16* Kv2   = (bf16*)(ws + 132291584);   // [154][1280]
  float* Outf = (float*)d_out;

  dim3 blk(256);

  // fused weight prep: one launch for all transposes + ctx cvt
  PrepArgs pa;
  const float* srcs[10] = {wq1, wk1, wv1, wo1, wq2, wk2, wv2, wo2, wff1, wff2};
  bf16* dsts[10] = {Wqkv1, Wqkv1 + 640 * 640, Wqkv1 + 2 * 640 * 640, Wo1t, Wq2t,
                    Wkv2t, Wkv2t + 640 * 768, Wo2t, Wff1t, Wff2t};
  int Rs[10] = {640, 640, 640, 640, 640, 768, 768, 640, 640, 2560};
  int Cs[10] = {640, 640, 640, 640, 640, 640, 640, 640, 5120, 640};
  int baseacc = 0;
  for (int j = 0; j < 10; ++j) {
    pa.src[j] = srcs[j];
    pa.dst[j] = dsts[j];
    pa.R[j] = Rs[j];
    pa.C[j] = Cs[j];
    pa.cb[j] = Cs[j] / 32;
    pa.base[j] = baseacc;
    baseacc += (Cs[j] / 32) * (Rs[j] / 32);
  }
  pa.cvtbase = baseacc;            // 8160
  pa.ctx = ctx;
  pa.ctxb = Ctxb;
  const int prep_blocks = baseacc + 116;
  prep_kernel<<<prep_blocks, blk, 0, stream>>>(pa);

  // self-attention block (QKV GEMM writes V transposed directly into Vt)
  ln_kernel<float><<<2048, blk, 0, stream>>>(x, ln1w, ln1b, Hln);
  gemm_kernel<3><<<dim3(64, 15), blk, 0, stream>>>(Hln, Wqkv1, nullptr, (const float*)Vt, Qkv, 8192, 640, 1920);
  flash_kernel<<<dim3(32, 16), blk, 0, stream>>>(Qkv, Vt, Ao);
  gemm64_kernel<4><<<dim3(128, 5), blk, 0, stream>>>(Ao, Wo1t, bo1, x, X2b, 640, 640);
  // cross-attention block
  ln_kernel<bf16><<<2048, blk, 0, stream>>>(X2b, ln2w, ln2b, Hln);
  gemm64_kernel<0><<<dim3(128, 5), blk, 0, stream>>>(Hln, Wq2t, nullptr, nullptr, Q2, 640, 640);
  gemm_kernel<0><<<dim3(2, 10), blk, 0, stream>>>(Ctxb, Wkv2t, nullptr, nullptr, Kv2, 154, 768, 1280);
  cross_kernel<<<dim3(32, 16), blk, 0, stream>>>(Q2, Kv2, Ao);
  gemm64_kernel<5><<<dim3(128, 5), blk, 0, stream>>>(Ao, Wo2t, bo2, X2b, X3b, 640, 640);
  // GEGLU FF block
  ln_kernel<bf16><<<2048, blk, 0, stream>>>(X3b, ln3w, ln3b, Hln);
  geglu_kernel<<<dim3(64, 40), blk, 0, stream>>>(Hln, Wff1t, bff1, Ffin);
  gemm64_kernel<6><<<dim3(128, 5), blk, 0, stream>>>(Ffin, Wff2t, bff2, X3b, Outf, 2560, 640);
}

// Round 19
// 340.879 us; speedup vs baseline: 1.1585x; 1.0082x over previous
//
#include <hip/hip_runtime.h>
#include <hip/hip_bf16.h>

typedef __hip_bfloat16 bf16;
typedef short s16x8 __attribute__((ext_vector_type(8)));
typedef short s16x4 __attribute__((ext_vector_type(4)));
typedef float f32x4 __attribute__((ext_vector_type(4)));

#define SCALE_DH 0.11180339887498949f   // 80^-0.5
#define QSCALE   0.16129820878f         // 80^-0.5 * log2(e)

static __device__ __forceinline__ float b2f(short u) {
  union { float f; unsigned int i; } x;
  x.i = ((unsigned int)(unsigned short)u) << 16;
  return x.f;
}

static __device__ __forceinline__ float tof(float x) { return x; }
static __device__ __forceinline__ float tof(bf16 x) { return __bfloat162float(x); }

static __device__ __forceinline__ void gload16(const bf16* g, bf16* l) {
  __builtin_amdgcn_global_load_lds((__attribute__((address_space(1))) const void*)g,
                                   (__attribute__((address_space(3))) void*)l, 16, 0, 0);
}

// ---------------- fused weight prep: 10 transposes + 1 cvt in one launch ----------------
struct PrepArgs {
  const float* src[10];
  bf16* dst[10];
  int R[10], C[10], cb[10], base[10];
  int cvtbase;
  const float* ctx;
  bf16* ctxb;
};

__global__ __launch_bounds__(256) void prep_kernel(PrepArgs a) {
  const int bid = blockIdx.x;
  if (bid >= a.cvtbase) {
    const int n = 154 * 768;
    int i = ((bid - a.cvtbase) * 256 + threadIdx.x) * 4;
    if (i + 4 <= n) {
      float4 v = *(const float4*)(a.ctx + i);
      a.ctxb[i + 0] = __float2bfloat16(v.x);
      a.ctxb[i + 1] = __float2bfloat16(v.y);
      a.ctxb[i + 2] = __float2bfloat16(v.z);
      a.ctxb[i + 3] = __float2bfloat16(v.w);
    } else {
      for (int k = i; k < n; ++k) a.ctxb[k] = __float2bfloat16(a.ctx[k]);
    }
    return;
  }
  int jid = 0;
#pragma unroll
  for (int k = 1; k < 10; ++k)
    if (bid >= a.base[k]) jid = k;
  const float* in = a.src[jid];
  bf16* out = a.dst[jid];
  const int R = a.R[jid], C = a.C[jid];
  const int lb = bid - a.base[jid];
  const int cblk = lb % a.cb[jid], rblk = lb / a.cb[jid];
  __shared__ float t[32][33];
  const int tx = threadIdx.x & 31, ty = threadIdx.x >> 5;
  const long r0 = (long)rblk * 32, c0 = (long)cblk * 32;
#pragma unroll
  for (int i = 0; i < 4; ++i)
    t[ty + 8 * i][tx] = in[(r0 + ty + 8 * i) * C + c0 + tx];
  __syncthreads();
#pragma unroll
  for (int i = 0; i < 4; ++i)
    out[(c0 + ty + 8 * i) * R + r0 + tx] = __float2bfloat16(t[tx][ty + 8 * i]);
}

// ---------------- LayerNorm D=640: T in -> bf16 out (one wave per row) ----------------
template <typename T>
__global__ __launch_bounds__(256) void ln_kernel(const T* __restrict__ x,
                                                 const float* __restrict__ w,
                                                 const float* __restrict__ b,
                                                 bf16* __restrict__ out) {
  const int wv = threadIdx.x >> 6, l = threadIdx.x & 63;
  const long row = (long)blockIdx.x * 4 + wv;
  const T* xr = x + row * 640;
  float v[10];
  float s = 0.f;
#pragma unroll
  for (int j = 0; j < 10; ++j) { v[j] = tof(xr[l + 64 * j]); s += v[j]; }
#pragma unroll
  for (int o = 32; o > 0; o >>= 1) s += __shfl_xor(s, o);
  const float mean = s * (1.f / 640.f);
  float vs = 0.f;
#pragma unroll
  for (int j = 0; j < 10; ++j) { float d = v[j] - mean; vs += d * d; }
#pragma unroll
  for (int o = 32; o > 0; o >>= 1) vs += __shfl_xor(vs, o);
  const float rstd = rsqrtf(vs * (1.f / 640.f) + 1e-5f);
  bf16* orow = out + row * 640;
#pragma unroll
  for (int j = 0; j < 10; ++j) {
    int d = l + 64 * j;
    orow[d] = __float2bfloat16((v[j] - mean) * rstd * w[d] + b[d]);
  }
}

// ---------------- GEMM 128x128: C[M,N] = A[M,K](bf16) * W, Bt = W^T [N][K] ----------------
// EPI 0: bf16 out. EPI 3 (QKV): bf16 out for col<1280; V cols written TRANSPOSED to vt (res param).
template <int EPI>
__global__ __launch_bounds__(256) void gemm_kernel(const bf16* __restrict__ A,
                                                   const bf16* __restrict__ Bt,
                                                   const float* __restrict__ bias,
                                                   const float* __restrict__ res,
                                                   void* __restrict__ Cout,
                                                   int M, int K, int ldc) {
  __shared__ bf16 Ash[128 * 64];
  __shared__ bf16 Bsh[128 * 64];
  const int tid = threadIdx.x, w = tid >> 6, l = tid & 63;
  const int m0 = blockIdx.x * 128, n0 = blockIdx.y * 128;
  const int mb = (w >> 1) * 64, nb = (w & 1) * 64;
  const int lo = l & 15, lg = l >> 4, lo7 = l & 7;
  const f32x4 fz = {0.f, 0.f, 0.f, 0.f};
  f32x4 acc[4][4];
#pragma unroll
  for (int i = 0; i < 4; ++i)
#pragma unroll
    for (int j = 0; j < 4; ++j) acc[i][j] = fz;

  const int g = tid;
  const int gr = g >> 3;
  const int gcsw = 8 * ((g & 7) ^ (gr & 7));
  const bf16* pa[4];
  const bf16* pb[4];
  bf16* la[4];
  bf16* lb[4];
#pragma unroll
  for (int s = 0; s < 4; ++s) {
    const int rl = gr + 32 * s;
    int ra = m0 + rl; if (ra >= M) ra = M - 1;
    pa[s] = A + (long)ra * K + gcsw;
    pb[s] = Bt + (long)(n0 + rl) * K + gcsw;
    la[s] = Ash + (g + 256 * s) * 8;
    lb[s] = Bsh + (g + 256 * s) * 8;
  }

  for (int k0 = 0; k0 < K; k0 += 64) {
    __syncthreads();
#pragma unroll
    for (int s = 0; s < 4; ++s) {
      gload16(pa[s], la[s]); pa[s] += 64;
      gload16(pb[s], lb[s]); pb[s] += 64;
    }
    __syncthreads();
#pragma unroll
    for (int kk = 0; kk < 2; ++kk) {
      const int sl = ((kk * 4 + lg) ^ lo7) * 8;
      s16x8 a[4], b[4];
#pragma unroll
      for (int i = 0; i < 4; ++i)
        a[i] = *(const s16x8*)(Ash + (mb + i * 16 + lo) * 64 + sl);
#pragma unroll
      for (int j = 0; j < 4; ++j)
        b[j] = *(const s16x8*)(Bsh + (nb + j * 16 + lo) * 64 + sl);
#pragma unroll
      for (int i = 0; i < 4; ++i)
#pragma unroll
        for (int j = 0; j < 4; ++j)
          acc[i][j] = __builtin_amdgcn_mfma_f32_16x16x32_bf16(a[i], b[j], acc[i][j], 0, 0, 0);
    }
  }
  const int rb = m0 + mb + lg * 4;
  const int cb = n0 + nb + lo;
#pragma unroll
  for (int i = 0; i < 4; ++i) {
#pragma unroll
    for (int j = 0; j < 4; ++j) {
      const int col = cb + j * 16;
      if (EPI == 3 && col >= 1280) {
        const int t = col - 1280;
        const int hh = t / 80, dh = t % 80;
        const int row0 = rb + i * 16;
        const int bb = row0 >> 12, n = row0 & 4095;
        s16x4 pk;
#pragma unroll
        for (int r = 0; r < 4; ++r)
          pk[r] = (short)__bfloat16_as_ushort(__float2bfloat16(acc[i][j][r]));
        bf16* vt = (bf16*)res;
        *(s16x4*)(vt + (long)(bb * 8 + hh) * 327680 + (long)dh * 4096 + n) = pk;
        continue;
      }
#pragma unroll
      for (int r = 0; r < 4; ++r) {
        const int row = rb + i * 16 + r;
        if (row < M)
          ((bf16*)Cout)[(long)row * ldc + col] = __float2bfloat16(acc[i][j][r]);
      }
    }
  }
}

// ---------------- GEMM 64x128 (N=640 GEMMs; M % 64 == 0) ----------------
// EPI 0: bf16 out, no bias. EPI 4: bf16 out = acc+bias+f32 res. EPI 5: bf16 out = acc+bias+bf16 res.
// EPI 6: f32 out = acc+bias+bf16 res.
template <int EPI>
__global__ __launch_bounds__(256) void gemm64_kernel(const bf16* __restrict__ A,
                                                     const bf16* __restrict__ Bt,
                                                     const float* __restrict__ bias,
                                                     const void* __restrict__ res,
                                                     void* __restrict__ Cout,
                                                     int K, int ldc) {
  __shared__ bf16 Ash[64 * 64];
  __shared__ bf16 Bsh[128 * 64];
  const int tid = threadIdx.x, w = tid >> 6, l = tid & 63;
  const int m0 = blockIdx.x * 64, n0 = blockIdx.y * 128;
  const int mb = (w & 1) * 32, nb = (w >> 1) * 64;
  const int lo = l & 15, lg = l >> 4, lo7 = l & 7;
  const f32x4 fz = {0.f, 0.f, 0.f, 0.f};
  f32x4 acc[2][4];
#pragma unroll
  for (int i = 0; i < 2; ++i)
#pragma unroll
    for (int j = 0; j < 4; ++j) acc[i][j] = fz;

  const int g = tid;
  const int gr = g >> 3;
  const int gcsw = 8 * ((g & 7) ^ (gr & 7));
  const bf16* pa[2];
  const bf16* pb[4];
  bf16* la[2];
  bf16* lb[4];
#pragma unroll
  for (int s = 0; s < 2; ++s) {
    pa[s] = A + (long)(m0 + gr + 32 * s) * K + gcsw;
    la[s] = Ash + (g + 256 * s) * 8;
  }
#pragma unroll
  for (int s = 0; s < 4; ++s) {
    pb[s] = Bt + (long)(n0 + gr + 32 * s) * K + gcsw;
    lb[s] = Bsh + (g + 256 * s) * 8;
  }

  for (int k0 = 0; k0 < K; k0 += 64) {
    __syncthreads();
#pragma unroll
    for (int s = 0; s < 2; ++s) { gload16(pa[s], la[s]); pa[s] += 64; }
#pragma unroll
    for (int s = 0; s < 4; ++s) { gload16(pb[s], lb[s]); pb[s] += 64; }
    __syncthreads();
#pragma unroll
    for (int kk = 0; kk < 2; ++kk) {
      const int sl = ((kk * 4 + lg) ^ lo7) * 8;
      s16x8 a[2], b[4];
#pragma unroll
      for (int i = 0; i < 2; ++i)
        a[i] = *(const s16x8*)(Ash + (mb + i * 16 + lo) * 64 + sl);
#pragma unroll
      for (int j = 0; j < 4; ++j)
        b[j] = *(const s16x8*)(Bsh + (nb + j * 16 + lo) * 64 + sl);
#pragma unroll
      for (int i = 0; i < 2; ++i)
#pragma unroll
        for (int j = 0; j < 4; ++j)
          acc[i][j] = __builtin_amdgcn_mfma_f32_16x16x32_bf16(a[i], b[j], acc[i][j], 0, 0, 0);
    }
  }
  const int rb = m0 + mb + lg * 4;
  const int cb = n0 + nb + lo;
#pragma unroll
  for (int i = 0; i < 2; ++i) {
#pragma unroll
    for (int j = 0; j < 4; ++j) {
      const int col = cb + j * 16;
      float bv = 0.f;
      if (EPI >= 4) bv = bias[col];
#pragma unroll
      for (int r = 0; r < 4; ++r) {
        const int row = rb + i * 16 + r;
        const long idx = (long)row * ldc + col;
        float v = acc[i][j][r] + bv;
        if (EPI == 4) {
          v += ((const float*)res)[idx];
          ((bf16*)Cout)[idx] = __float2bfloat16(v);
        } else if (EPI == 5) {
          v += __bfloat162float(((const bf16*)res)[idx]);
          ((bf16*)Cout)[idx] = __float2bfloat16(v);
        } else if (EPI == 6) {
          v += __bfloat162float(((const bf16*)res)[idx]);
          ((float*)Cout)[idx] = v;
        } else {
          ((bf16*)Cout)[idx] = __float2bfloat16(v);
        }
      }
    }
  }
}

// ---------------- Flash self-attention v16: v15 + XCD-aware block remap (each XCD serves 2 heads) ----------------
__global__ __launch_bounds__(256, 3) void flash_kernel(const bf16* __restrict__ qkv,
                                                       const bf16* __restrict__ vT,
                                                       bf16* __restrict__ out) {
  __shared__ bf16 Ksh[2][64 * 80];
  __shared__ bf16 Vsh[2][80 * 64];
  // XCD-aware remap: dispatch round-robins blockIdx.x % 8 across XCDs.
  // bh = xcd*2 + (wi&1): each XCD touches only 2 heads -> K/V working set ~5.2MB ~= L2.
  const int bid = blockIdx.x;
  const int xcd = bid & 7, wi = bid >> 3;
  const int bh = xcd * 2 + (wi & 1);
  const int qx = wi >> 1;
  const int b = bh >> 3, h = bh & 7;
  const int tid = threadIdx.x, w = tid >> 6, l = tid & 63;
  const int r0 = qx * 128 + w * 32;
  const int lg = l >> 4, lo = l & 15, lo7 = l & 7;
  const int sb = l & 48;
  const s16x8 sz = {0, 0, 0, 0, 0, 0, 0, 0};
  const f32x4 fz = {0.f, 0.f, 0.f, 0.f};

  s16x8 qa[2][3];
#pragma unroll
  for (int gq = 0; gq < 2; ++gq) {
    const bf16* qp = qkv + (long)(b * 4096 + r0 + gq * 16 + lo) * 1920 + h * 80;
    qa[gq][0] = *(const s16x8*)(qp + lg * 8);
    qa[gq][1] = *(const s16x8*)(qp + 32 + lg * 8);
    qa[gq][2] = (lg < 2) ? *(const s16x8*)(qp + 64 + lg * 8) : sz;
#pragma unroll
    for (int f = 0; f < 3; ++f) {
      s16x8 q = qa[gq][f], r;
#pragma unroll
      for (int i = 0; i < 8; ++i)
        r[i] = (short)(__bfloat16_as_ushort(__float2bfloat16(b2f(q[i]) * QSCALE)));
      qa[gq][f] = r;
    }
  }

  const bf16* kp[3];
  const int nbatch = (w < 2) ? 3 : 2;
#pragma unroll
  for (int it = 0; it < 3; ++it) {
    int g = tid + 256 * it;
    int gc = (g < 640) ? g : 0;
    int krow = gc / 10, ksl = gc % 10;
    int ksrc = (ksl < 8) ? (ksl ^ (krow & 7)) : (8 + ((ksl - 8) ^ ((krow >> 2) & 1)));
    kp[it] = qkv + (long)(b * 4096 + krow) * 1920 + 640 + h * 80 + ksrc * 8;
  }
  const bf16* vp0 = vT + (long)bh * 327680 + (long)(tid >> 3) * 4096 +
                    (((tid & 7) ^ ((tid >> 3) & 7)) * 8);
  const int soff0 = tid * 8;

  const int voff0 = (((lg >> 1) + 0) ^ lo7) * 8 + 4 * (lg & 1);
  const int voff1 = (((lg >> 1) + 2) ^ lo7) * 8 + 4 * (lg & 1);
  const int voff2 = (((lg >> 1) + 4) ^ lo7) * 8 + 4 * (lg & 1);
  const int voff3 = (((lg >> 1) + 6) ^ lo7) * 8 + 4 * (lg & 1);

  float lrA = 0.f, lrB = 0.f;
  f32x4 oA[5], oB[5];
#pragma unroll
  for (int dt = 0; dt < 5; ++dt) { oA[dt] = fz; oB[dt] = fz; }

  // prologue: stage tile 0 into buffer 0
#pragma unroll
  for (int it = 0; it < 3; ++it) {
    if (it < nbatch) {
      gload16(kp[it], Ksh[0] + soff0 + 2048 * it); kp[it] += 64 * 1920;
      gload16(vp0 + (long)it * 131072, Vsh[0] + soff0 + 2048 * it);
    }
  }
  __syncthreads();

  for (int kt = 0; kt < 64; ++kt) {
    const int cur = kt & 1;
    const bf16* kbuf = Ksh[cur];
    const bf16* vbuf = Vsh[cur];

    if (kt < 63) {
#pragma unroll
      for (int it = 0; it < 3; ++it) {
        if (it < nbatch) {
          gload16(kp[it], Ksh[cur ^ 1] + soff0 + 2048 * it); kp[it] += 64 * 1920;
          gload16(vp0 + (long)(kt + 1) * 64 + (long)it * 131072, Vsh[cur ^ 1] + soff0 + 2048 * it);
        }
      }
    }

    unsigned paA[8], paB[8];
    f32x4 s0A, s0B, s1A, s1B;
    {
      s16x8 kb0 = *(const s16x8*)(kbuf + lo * 80 + ((lg ^ lo7)) * 8);
      s16x8 kb1 = *(const s16x8*)(kbuf + lo * 80 + (((4 + lg) ^ lo7)) * 8);
      s16x8 kb2 = (lg < 2) ? *(const s16x8*)(kbuf + lo * 80 + 64 + ((lg ^ ((lo >> 2) & 1))) * 8) : sz;
      __builtin_amdgcn_s_setprio(1);
      s0A = __builtin_amdgcn_mfma_f32_16x16x32_bf16(kb0, qa[0][0], fz, 0, 0, 0);
      s0A = __builtin_amdgcn_mfma_f32_16x16x32_bf16(kb1, qa[0][1], s0A, 0, 0, 0);
      s0A = __builtin_amdgcn_mfma_f32_16x16x32_bf16(kb2, qa[0][2], s0A, 0, 0, 0);
      s0B = __builtin_amdgcn_mfma_f32_16x16x32_bf16(kb0, qa[1][0], fz, 0, 0, 0);
      s0B = __builtin_amdgcn_mfma_f32_16x16x32_bf16(kb1, qa[1][1], s0B, 0, 0, 0);
      s0B = __builtin_amdgcn_mfma_f32_16x16x32_bf16(kb2, qa[1][2], s0B, 0, 0, 0);
      __builtin_amdgcn_s_setprio(0);
    }
#pragma unroll
    for (int ntl = 1; ntl <= 4; ++ntl) {
      if (ntl < 4) {
        s16x8 kb0 = *(const s16x8*)(kbuf + (ntl * 16 + lo) * 80 + ((lg ^ lo7)) * 8);
        s16x8 kb1 = *(const s16x8*)(kbuf + (ntl * 16 + lo) * 80 + (((4 + lg) ^ lo7)) * 8);
        s16x8 kb2 = (lg < 2)
                        ? *(const s16x8*)(kbuf + (ntl * 16 + lo) * 80 + 64 + ((lg ^ ((lo >> 2) & 1))) * 8)
                        : sz;
        __builtin_amdgcn_s_setprio(1);
        s1A = __builtin_amdgcn_mfma_f32_16x16x32_bf16(kb0, qa[0][0], fz, 0, 0, 0);
        s1A = __builtin_amdgcn_mfma_f32_16x16x32_bf16(kb1, qa[0][1], s1A, 0, 0, 0);
        s1A = __builtin_amdgcn_mfma_f32_16x16x32_bf16(kb2, qa[0][2], s1A, 0, 0, 0);
        s1B = __builtin_amdgcn_mfma_f32_16x16x32_bf16(kb0, qa[1][0], fz, 0, 0, 0);
        s1B = __builtin_amdgcn_mfma_f32_16x16x32_bf16(kb1, qa[1][1], s1B, 0, 0, 0);
        s1B = __builtin_amdgcn_mfma_f32_16x16x32_bf16(kb2, qa[1][2], s1B, 0, 0, 0);
        __builtin_amdgcn_s_setprio(0);
      }
      {
        const int pidx = ntl - 1;
        float a0 = __builtin_amdgcn_exp2f(s0A[0]);
        float a1 = __builtin_amdgcn_exp2f(s0A[1]);
        float a2 = __builtin_amdgcn_exp2f(s0A[2]);
        float a3 = __builtin_amdgcn_exp2f(s0A[3]);
        lrA += (a0 + a1) + (a2 + a3);
        unsigned u0, u1;
        asm("v_cvt_pk_bf16_f32 %0, %1, %2" : "=v"(u0) : "v"(a0), "v"(a1));
        asm("v_cvt_pk_bf16_f32 %0, %1, %2" : "=v"(u1) : "v"(a2), "v"(a3));
        paA[pidx * 2] = u0;
        paA[pidx * 2 + 1] = u1;
        float b0 = __builtin_amdgcn_exp2f(s0B[0]);
        float b1 = __builtin_amdgcn_exp2f(s0B[1]);
        float b2 = __builtin_amdgcn_exp2f(s0B[2]);
        float b3 = __builtin_amdgcn_exp2f(s0B[3]);
        lrB += (b0 + b1) + (b2 + b3);
        asm("v_cvt_pk_bf16_f32 %0, %1, %2" : "=v"(u0) : "v"(b0), "v"(b1));
        asm("v_cvt_pk_bf16_f32 %0, %1, %2" : "=v"(u1) : "v"(b2), "v"(b3));
        paB[pidx * 2] = u0;
        paB[pidx * 2 + 1] = u1;
      }
      s0A = s1A;
      s0B = s1B;
    }

    typedef unsigned u32x2 __attribute__((ext_vector_type(2)));
    s16x8 frA0, frA1, frB0, frB1;
    {
      u32x2* p;
      p = (u32x2*)&frA0; p[0] = (u32x2){paA[0], paA[1]}; p[1] = (u32x2){paA[2], paA[3]};
      p = (u32x2*)&frA1; p[0] = (u32x2){paA[4], paA[5]}; p[1] = (u32x2){paA[6], paA[7]};
      p = (u32x2*)&frB0; p[0] = (u32x2){paB[0], paB[1]}; p[1] = (u32x2){paB[2], paB[3]};
      p = (u32x2*)&frB1; p[0] = (u32x2){paB[4], paB[5]}; p[1] = (u32x2){paB[6], paB[7]};
    }

    __builtin_amdgcn_s_setprio(1);
#pragma unroll
    for (int dt = 0; dt < 5; ++dt) {
      const bf16* vrow = vbuf + (dt * 16 + lo) * 64;
      s16x4 w00 = *(const s16x4*)(vrow + voff0);
      s16x4 w01 = *(const s16x4*)(vrow + voff1);
      s16x4 w10 = *(const s16x4*)(vrow + voff2);
      s16x4 w11 = *(const s16x4*)(vrow + voff3);
      s16x8 vb0 = __builtin_shufflevector(w00, w01, 0, 1, 2, 3, 4, 5, 6, 7);
      s16x8 vb1 = __builtin_shufflevector(w10, w11, 0, 1, 2, 3, 4, 5, 6, 7);
      oA[dt] = __builtin_amdgcn_mfma_f32_16x16x32_bf16(frA0, vb0, oA[dt], 0, 0, 0);
      oA[dt] = __builtin_amdgcn_mfma_f32_16x16x32_bf16(frA1, vb1, oA[dt], 0, 0, 0);
      oB[dt] = __builtin_amdgcn_mfma_f32_16x16x32_bf16(frB0, vb0, oB[dt], 0, 0, 0);
      oB[dt] = __builtin_amdgcn_mfma_f32_16x16x32_bf16(frB1, vb1, oB[dt], 0, 0, 0);
    }
    __builtin_amdgcn_s_setprio(0);

    __syncthreads();   // waves done reading buf[cur]; drains K/V(t+1) into buf[cur^1]
  }

  {
    float ssum = lrA;
    ssum += __shfl_xor(ssum, 16);
    ssum += __shfl_xor(ssum, 32);
    const float linv = 1.f / ssum;
    float li[4];
#pragma unroll
    for (int r = 0; r < 4; ++r) li[r] = __shfl(linv, sb + lg * 4 + r);
    bf16* ob = out + (long)(b * 4096 + r0 + lg * 4) * 640 + h * 80 + lo;
#pragma unroll
    for (int r = 0; r < 4; ++r)
#pragma unroll
      for (int dt = 0; dt < 5; ++dt)
        ob[(long)r * 640 + dt * 16] = __float2bfloat16(oA[dt][r] * li[r]);
  }
  {
    float ssum = lrB;
    ssum += __shfl_xor(ssum, 16);
    ssum += __shfl_xor(ssum, 32);
    const float linv = 1.f / ssum;
    float li[4];
#pragma unroll
    for (int r = 0; r < 4; ++r) li[r] = __shfl(linv, sb + lg * 4 + r);
    bf16* ob = out + (long)(b * 4096 + r0 + 16 + lg * 4) * 640 + h * 80 + lo;
#pragma unroll
    for (int r = 0; r < 4; ++r)
#pragma unroll
      for (int dt = 0; dt < 5; ++dt)
        ob[(long)r * 640 + dt * 16] = __float2bfloat16(oB[dt][r] * li[r]);
  }
}

// ---------------- Cross-attention v2 (MFMA): 77 keys padded to 80, P in registers ----------------
__global__ __launch_bounds__(256) void cross_kernel(const bf16* __restrict__ q2,
                                                    const bf16* __restrict__ kv2,
                                                    bf16* __restrict__ out) {
  __shared__ bf16 Ksh2[80 * 88];
  __shared__ bf16 Vsh2[80 * 88];
  const int bh = blockIdx.y, b = bh >> 3, h = bh & 7;
  const int tid = threadIdx.x, w = tid >> 6, l = tid & 63;
  const int r0 = blockIdx.x * 128 + w * 32;
  const int lg = l >> 4, lo = l & 15;
  const int sb = l & 48;
  const s16x8 sz = {0, 0, 0, 0, 0, 0, 0, 0};
  const f32x4 fz = {0.f, 0.f, 0.f, 0.f};

  s16x8 qa[2][3];
#pragma unroll
  for (int gq = 0; gq < 2; ++gq) {
    const bf16* qp = q2 + (long)(b * 4096 + r0 + gq * 16 + lo) * 640 + h * 80;
    qa[gq][0] = *(const s16x8*)(qp + lg * 8);
    qa[gq][1] = *(const s16x8*)(qp + 32 + lg * 8);
    qa[gq][2] = (lg < 2) ? *(const s16x8*)(qp + 64 + lg * 8) : sz;
#pragma unroll
    for (int f = 0; f < 3; ++f) {
      s16x8 q = qa[gq][f], r;
#pragma unroll
      for (int i = 0; i < 8; ++i)
        r[i] = (short)(__bfloat16_as_ushort(__float2bfloat16(b2f(q[i]) * QSCALE)));
      qa[gq][f] = r;
    }
  }

  for (int c = tid; c < 800; c += 256) {
    int row = c / 10, s = c % 10;
    s16x8 v = sz;
    if (row < 77)
      v = *(const s16x8*)(kv2 + (long)(b * 77 + row) * 1280 + h * 80 + s * 8);
    *(s16x8*)(Ksh2 + row * 88 + s * 8) = v;
  }
  for (int c = tid; c < 770; c += 256) {
    int j = c / 10, d8 = (c % 10) * 8;
    s16x8 v = *(const s16x8*)(kv2 + (long)(b * 77 + j) * 1280 + 640 + h * 80 + d8);
    const short* vs = (const short*)&v;
#pragma unroll
    for (int i = 0; i < 8; ++i) ((short*)Vsh2)[(d8 + i) * 88 + j] = vs[i];
  }
  if (tid < 240) {
    int d = tid / 3, j = 77 + tid % 3;
    ((short*)Vsh2)[d * 88 + j] = 0;
  }
  __syncthreads();

  float lrA = 0.f, lrB = 0.f;
  f32x4 oA[5], oB[5];
#pragma unroll
  for (int dt = 0; dt < 5; ++dt) { oA[dt] = fz; oB[dt] = fz; }

  unsigned paA[10], paB[10];
  f32x4 s0A, s0B, s1A, s1B;
  {
    s16x8 kb0 = *(const s16x8*)(Ksh2 + lo * 88 + lg * 8);
    s16x8 kb1 = *(const s16x8*)(Ksh2 + lo * 88 + 32 + lg * 8);
    s16x8 kb2 = (lg < 2) ? *(const s16x8*)(Ksh2 + lo * 88 + 64 + lg * 8) : sz;
    __builtin_amdgcn_s_setprio(1);
    s0A = __builtin_amdgcn_mfma_f32_16x16x32_bf16(kb0, qa[0][0], fz, 0, 0, 0);
    s0A = __builtin_amdgcn_mfma_f32_16x16x32_bf16(kb1, qa[0][1], s0A, 0, 0, 0);
    s0A = __builtin_amdgcn_mfma_f32_16x16x32_bf16(kb2, qa[0][2], s0A, 0, 0, 0);
    s0B = __builtin_amdgcn_mfma_f32_16x16x32_bf16(kb0, qa[1][0], fz, 0, 0, 0);
    s0B = __builtin_amdgcn_mfma_f32_16x16x32_bf16(kb1, qa[1][1], s0B, 0, 0, 0);
    s0B = __builtin_amdgcn_mfma_f32_16x16x32_bf16(kb2, qa[1][2], s0B, 0, 0, 0);
    __builtin_amdgcn_s_setprio(0);
  }
#pragma unroll
  for (int ntl = 1; ntl <= 5; ++ntl) {
    if (ntl < 5) {
      s16x8 kb0 = *(const s16x8*)(Ksh2 + (ntl * 16 + lo) * 88 + lg * 8);
      s16x8 kb1 = *(const s16x8*)(Ksh2 + (ntl * 16 + lo) * 88 + 32 + lg * 8);
      s16x8 kb2 = (lg < 2) ? *(const s16x8*)(Ksh2 + (ntl * 16 + lo) * 88 + 64 + lg * 8) : sz;
      __builtin_amdgcn_s_setprio(1);
      s1A = __builtin_amdgcn_mfma_f32_16x16x32_bf16(kb0, qa[0][0], fz, 0, 0, 0);
      s1A = __builtin_amdgcn_mfma_f32_16x16x32_bf16(kb1, qa[0][1], s1A, 0, 0, 0);
      s1A = __builtin_amdgcn_mfma_f32_16x16x32_bf16(kb2, qa[0][2], s1A, 0, 0, 0);
      s1B = __builtin_amdgcn_mfma_f32_16x16x32_bf16(kb0, qa[1][0], fz, 0, 0, 0);
      s1B = __builtin_amdgcn_mfma_f32_16x16x32_bf16(kb1, qa[1][1], s1B, 0, 0, 0);
      s1B = __builtin_amdgcn_mfma_f32_16x16x32_bf16(kb2, qa[1][2], s1B, 0, 0, 0);
      __builtin_amdgcn_s_setprio(0);
    }
    {
      const int pidx = ntl - 1;
      float a0 = __builtin_amdgcn_exp2f(s0A[0]);
      float a1 = __builtin_amdgcn_exp2f(s0A[1]);
      float a2 = __builtin_amdgcn_exp2f(s0A[2]);
      float a3 = __builtin_amdgcn_exp2f(s0A[3]);
      float b0 = __builtin_amdgcn_exp2f(s0B[0]);
      float b1 = __builtin_amdgcn_exp2f(s0B[1]);
      float b2 = __builtin_amdgcn_exp2f(s0B[2]);
      float b3 = __builtin_amdgcn_exp2f(s0B[3]);
      if (pidx == 4) {
        if (lg * 4 + 1 >= 13) { a1 = 0.f; b1 = 0.f; }
        if (lg * 4 + 2 >= 13) { a2 = 0.f; b2 = 0.f; }
        if (lg * 4 + 3 >= 13) { a3 = 0.f; b3 = 0.f; }
      }
      lrA += (a0 + a1) + (a2 + a3);
      lrB += (b0 + b1) + (b2 + b3);
      unsigned u0, u1;
      asm("v_cvt_pk_bf16_f32 %0, %1, %2" : "=v"(u0) : "v"(a0), "v"(a1));
      asm("v_cvt_pk_bf16_f32 %0, %1, %2" : "=v"(u1) : "v"(a2), "v"(a3));
      paA[pidx * 2] = u0;
      paA[pidx * 2 + 1] = u1;
      asm("v_cvt_pk_bf16_f32 %0, %1, %2" : "=v"(u0) : "v"(b0), "v"(b1));
      asm("v_cvt_pk_bf16_f32 %0, %1, %2" : "=v"(u1) : "v"(b2), "v"(b3));
      paB[pidx * 2] = u0;
      paB[pidx * 2 + 1] = u1;
    }
    s0A = s1A;
    s0B = s1B;
  }

  typedef unsigned u32x2 __attribute__((ext_vector_type(2)));
  s16x8 frA0, frA1, frA2, frB0, frB1, frB2;
  {
    u32x2* p;
    p = (u32x2*)&frA0; p[0] = (u32x2){paA[0], paA[1]}; p[1] = (u32x2){paA[2], paA[3]};
    p = (u32x2*)&frA1; p[0] = (u32x2){paA[4], paA[5]}; p[1] = (u32x2){paA[6], paA[7]};
    p = (u32x2*)&frA2; p[0] = (u32x2){paA[8], paA[9]}; p[1] = (u32x2){0u, 0u};
    p = (u32x2*)&frB0; p[0] = (u32x2){paB[0], paB[1]}; p[1] = (u32x2){paB[2], paB[3]};
    p = (u32x2*)&frB1; p[0] = (u32x2){paB[4], paB[5]}; p[1] = (u32x2){paB[6], paB[7]};
    p = (u32x2*)&frB2; p[0] = (u32x2){paB[8], paB[9]}; p[1] = (u32x2){0u, 0u};
  }

  __builtin_amdgcn_s_setprio(1);
#pragma unroll
  for (int dt = 0; dt < 5; ++dt) {
    const bf16* vrow = Vsh2 + (dt * 16 + lo) * 88;
    s16x4 w00 = *(const s16x4*)(vrow + 4 * lg);
    s16x4 w01 = *(const s16x4*)(vrow + 16 + 4 * lg);
    s16x4 w10 = *(const s16x4*)(vrow + 32 + 4 * lg);
    s16x4 w11 = *(const s16x4*)(vrow + 48 + 4 * lg);
    s16x4 w20 = *(const s16x4*)(vrow + 64 + 4 * lg);
    s16x8 vb0 = __builtin_shufflevector(w00, w01, 0, 1, 2, 3, 4, 5, 6, 7);
    s16x8 vb1 = __builtin_shufflevector(w10, w11, 0, 1, 2, 3, 4, 5, 6, 7);
    s16x8 vb2 = __builtin_shufflevector(w20, w20, 0, 1, 2, 3, 0, 1, 2, 3);
    oA[dt] = __builtin_amdgcn_mfma_f32_16x16x32_bf16(frA0, vb0, oA[dt], 0, 0, 0);
    oA[dt] = __builtin_amdgcn_mfma_f32_16x16x32_bf16(frA1, vb1, oA[dt], 0, 0, 0);
    oA[dt] = __builtin_amdgcn_mfma_f32_16x16x32_bf16(frA2, vb2, oA[dt], 0, 0, 0);
    oB[dt] = __builtin_amdgcn_mfma_f32_16x16x32_bf16(frB0, vb0, oB[dt], 0, 0, 0);
    oB[dt] = __builtin_amdgcn_mfma_f32_16x16x32_bf16(frB1, vb1, oB[dt], 0, 0, 0);
    oB[dt] = __builtin_amdgcn_mfma_f32_16x16x32_bf16(frB2, vb2, oB[dt], 0, 0, 0);
  }
  __builtin_amdgcn_s_setprio(0);

  {
    float ssum = lrA;
    ssum += __shfl_xor(ssum, 16);
    ssum += __shfl_xor(ssum, 32);
    const float linv = 1.f / ssum;
    float li[4];
#pragma unroll
    for (int r = 0; r < 4; ++r) li[r] = __shfl(linv, sb + lg * 4 + r);
    bf16* ob = out + (long)(b * 4096 + r0 + lg * 4) * 640 + h * 80 + lo;
#pragma unroll
    for (int r = 0; r < 4; ++r)
#pragma unroll
      for (int dt = 0; dt < 5; ++dt)
        ob[(long)r * 640 + dt * 16] = __float2bfloat16(oA[dt][r] * li[r]);
  }
  {
    float ssum = lrB;
    ssum += __shfl_xor(ssum, 16);
    ssum += __shfl_xor(ssum, 32);
    const float linv = 1.f / ssum;
    float li[4];
#pragma unroll
    for (int r = 0; r < 4; ++r) li[r] = __shfl(linv, sb + lg * 4 + r);
    bf16* ob = out + (long)(b * 4096 + r0 + 16 + lg * 4) * 640 + h * 80 + lo;
#pragma unroll
    for (int r = 0; r < 4; ++r)
#pragma unroll
      for (int dt = 0; dt < 5; ++dt)
        ob[(long)r * 640 + dt * 16] = __float2bfloat16(oB[dt][r] * li[r]);
  }
}

// ---------------- FF1 + GEGLU fused (128x64 tile, BK=64, swizzled LDS) ----------------
__global__ __launch_bounds__(256) void geglu_kernel(const bf16* __restrict__ A,
                                                    const bf16* __restrict__ Bt,
                                                    const float* __restrict__ bias,
                                                    bf16* __restrict__ Cout) {
  __shared__ bf16 Ash[128 * 64];
  __shared__ bf16 Bsh[2][64 * 64];
  const int tid = threadIdx.x, w = tid >> 6, l = tid & 63;
  const int m0 = blockIdx.x * 128, n0 = blockIdx.y * 64;
  const int lo = l & 15, lg = l >> 4, lo7 = l & 7;
  const int mb = w * 32;
  const f32x4 fz = {0.f, 0.f, 0.f, 0.f};
  f32x4 accA[2][4], accG[2][4];
#pragma unroll
  for (int i = 0; i < 2; ++i)
#pragma unroll
    for (int j = 0; j < 4; ++j) { accA[i][j] = fz; accG[i][j] = fz; }

  const int g = tid;
  const int gr = g >> 3;
  const int gcsw = 8 * ((g & 7) ^ (gr & 7));
  const bf16* pa[4];
  const bf16* pb[2][2];
  bf16* la[4];
  bf16* lb[2][2];
#pragma unroll
  for (int s = 0; s < 4; ++s) {
    pa[s] = A + (long)(m0 + gr + 32 * s) * 640 + gcsw;
    la[s] = Ash + (g + 256 * s) * 8;
  }
#pragma unroll
  for (int q = 0; q < 2; ++q)
#pragma unroll
    for (int s = 0; s < 2; ++s) {
      pb[q][s] = Bt + (long)(n0 + q * 2560 + gr + 32 * s) * 640 + gcsw;
      lb[q][s] = Bsh[q] + (g + 256 * s) * 8;
    }

  for (int k0 = 0; k0 < 640; k0 += 64) {
    __syncthreads();
#pragma unroll
    for (int s = 0; s < 4; ++s) { gload16(pa[s], la[s]); pa[s] += 64; }
#pragma unroll
    for (int q = 0; q < 2; ++q)
#pragma unroll
      for (int s = 0; s < 2; ++s) { gload16(pb[q][s], lb[q][s]); pb[q][s] += 64; }
    __syncthreads();
#pragma unroll
    for (int kk = 0; kk < 2; ++kk) {
      const int sl = ((kk * 4 + lg) ^ lo7) * 8;
      s16x8 a[2], ba[4], bg[4];
#pragma unroll
      for (int i = 0; i < 2; ++i)
        a[i] = *(const s16x8*)(Ash + (mb + i * 16 + lo) * 64 + sl);
#pragma unroll
      for (int j = 0; j < 4; ++j) {
        ba[j] = *(const s16x8*)(Bsh[0] + (j * 16 + lo) * 64 + sl);
        bg[j] = *(const s16x8*)(Bsh[1] + (j * 16 + lo) * 64 + sl);
      }
#pragma unroll
      for (int i = 0; i < 2; ++i)
#pragma unroll
        for (int j = 0; j < 4; ++j) {
          accA[i][j] = __builtin_amdgcn_mfma_f32_16x16x32_bf16(a[i], ba[j], accA[i][j], 0, 0, 0);
          accG[i][j] = __builtin_amdgcn_mfma_f32_16x16x32_bf16(a[i], bg[j], accG[i][j], 0, 0, 0);
        }
    }
  }
#pragma unroll
  for (int i = 0; i < 2; ++i) {
#pragma unroll
    for (int j = 0; j < 4; ++j) {
      const int col = n0 + j * 16 + lo;
      const float bA = bias[col];
      const float bG = bias[2560 + col];
#pragma unroll
      for (int r = 0; r < 4; ++r) {
        const long row = m0 + mb + i * 16 + lg * 4 + r;
        const float av = accA[i][j][r] + bA;
        const float gv = accG[i][j][r] + bG;
        const float ge = 0.5f * gv * (1.f + erff(gv * 0.70710678118654752f));
        Cout[row * 2560 + col] = __float2bfloat16(av * ge);
      }
    }
  }
}

// ---------------- host launch ----------------
extern "C" void kernel_launch(void* const* d_in, const int* in_sizes, int n_in,
                              void* d_out, int out_size, void* d_ws, size_t ws_size,
                              hipStream_t stream) {
  (void)in_sizes; (void)n_in; (void)out_size; (void)ws_size;
  const float* x    = (const float*)d_in[0];
  const float* ctx  = (const float*)d_in[1];
  const float* ln1w = (const float*)d_in[2];
  const float* ln1b = (const float*)d_in[3];
  const float* ln2w = (const float*)d_in[4];
  const float* ln2b = (const float*)d_in[5];
  const float* ln3w = (const float*)d_in[6];
  const float* ln3b = (const float*)d_in[7];
  const float* wq1  = (const float*)d_in[8];
  const float* wk1  = (const float*)d_in[9];
  const float* wv1  = (const float*)d_in[10];
  const float* wo1  = (const float*)d_in[11];
  const float* bo1  = (const float*)d_in[12];
  const float* wq2  = (const float*)d_in[13];
  const float* wk2  = (const float*)d_in[14];
  const float* wv2  = (const float*)d_in[15];
  const float* wo2  = (const float*)d_in[16];
  const float* bo2  = (const float*)d_in[17];
  const float* wff1 = (const float*)d_in[18];
  const float* bff1 = (const float*)d_in[19];
  const float* wff2 = (const float*)d_in[20];
  const float* bff2 = (const float*)d_in[21];

  char* ws = (char*)d_ws;
  bf16* Wqkv1 = (bf16*)(ws + 0);           // [1920][640]
  bf16* Wo1t  = (bf16*)(ws + 2457600);     // [640][640]
  bf16* Wq2t  = (bf16*)(ws + 3276800);     // [640][640]
  bf16* Wkv2t = (bf16*)(ws + 4096000);     // [1280][768]
  bf16* Wo2t  = (bf16*)(ws + 6062080);     // [640][640]
  bf16* Wff1t = (bf16*)(ws + 6881280);     // [5120][640]
  bf16* Wff2t = (bf16*)(ws + 13434880);    // [640][2560]
  bf16* Ctxb  = (bf16*)(ws + 16711680);    // [154][768]
  bf16* Hln   = (bf16*)(ws + 16948224);    // [8192][640]
  bf16* X2b   = (bf16*)(ws + 27433984);    // [8192][640] bf16 residual
  bf16* X3b   = (bf16*)(ws + 48405504);    // [8192][640] bf16 residual
  bf16* Qkv   = (bf16*)(ws + 69377024);    // [8192][1920]
  bf16* Ffin  = Qkv;                       // reuse: [8192][2560]
  bf16* Vt    = (bf16*)(ws + 100834304);   // [16][80][4096]
  bf16* Ao    = (bf16*)(ws + 111320064);   // [8192][640]
  bf16* Q2    = (bf16*)(ws + 121805824);   // [8192][640]
  bf16* Kv2   = (bf16*)(ws + 132291584);   // [154][1280]
  float* Outf = (float*)d_out;

  dim3 blk(256);

  // fused weight prep: one launch for all transposes + ctx cvt
  PrepArgs pa;
  const float* srcs[10] = {wq1, wk1, wv1, wo1, wq2, wk2, wv2, wo2, wff1, wff2};
  bf16* dsts[10] = {Wqkv1, Wqkv1 + 640 * 640, Wqkv1 + 2 * 640 * 640, Wo1t, Wq2t,
                    Wkv2t, Wkv2t + 640 * 768, Wo2t, Wff1t, Wff2t};
  int Rs[10] = {640, 640, 640, 640, 640, 768, 768, 640, 640, 2560};
  int Cs[10] = {640, 640, 640, 640, 640, 640, 640, 640, 5120, 640};
  int baseacc = 0;
  for (int j = 0; j < 10; ++j) {
    pa.src[j] = srcs[j];
    pa.dst[j] = dsts[j];
    pa.R[j] = Rs[j];
    pa.C[j] = Cs[j];
    pa.cb[j] = Cs[j] / 32;
    pa.base[j] = baseacc;
    baseacc += (Cs[j] / 32) * (Rs[j] / 32);
  }
  pa.cvtbase = baseacc;            // 8160
  pa.ctx = ctx;
  pa.ctxb = Ctxb;
  const int prep_blocks = baseacc + 116;
  prep_kernel<<<prep_blocks, blk, 0, stream>>>(pa);

  // self-attention block (QKV GEMM writes V transposed directly into Vt)
  ln_kernel<float><<<2048, blk, 0, stream>>>(x, ln1w, ln1b, Hln);
  gemm_kernel<3><<<dim3(64, 15), blk, 0, stream>>>(Hln, Wqkv1, nullptr, (const float*)Vt, Qkv, 8192, 640, 1920);
  flash_kernel<<<512, blk, 0, stream>>>(Qkv, Vt, Ao);
  gemm64_kernel<4><<<dim3(128, 5), blk, 0, stream>>>(Ao, Wo1t, bo1, x, X2b, 640, 640);
  // cross-attention block
  ln_kernel<bf16><<<2048, blk, 0, stream>>>(X2b, ln2w, ln2b, Hln);
  gemm64_kernel<0><<<dim3(128, 5), blk, 0, stream>>>(Hln, Wq2t, nullptr, nullptr, Q2, 640, 640);
  gemm_kernel<0><<<dim3(2, 10), blk, 0, stream>>>(Ctxb, Wkv2t, nullptr, nullptr, Kv2, 154, 768, 1280);
  cross_kernel<<<dim3(32, 16), blk, 0, stream>>>(Q2, Kv2, Ao);
  gemm64_kernel<5><<<dim3(128, 5), blk, 0, stream>>>(Ao, Wo2t, bo2, X2b, X3b, 640, 640);
  // GEGLU FF block
  ln_kernel<bf16><<<2048, blk, 0, stream>>>(X3b, ln3w, ln3b, Hln);
  geglu_kernel<<<dim3(64, 40), blk, 0, stream>>>(Hln, Wff1t, bff1, Ffin);
  gemm64_kernel<6><<<dim3(128, 5), blk, 0, stream>>>(Ffin, Wff2t, bff2, X3b, Outf, 2560, 640);
}